// Round 4
// baseline (510.747 us; speedup 1.0000x reference)
//
#include <hip/hip_runtime.h>

#define N_NODES 100000
#define N_EDGES 1600000
#define D 64
#define NEG_SLOPE 0.2f
#define SM_EPS 1e-16f

#define BSHIFT 9
#define BSIZE (1 << BSHIFT)                          // 512 dsts per bucket
#define NB ((N_NODES + BSIZE - 1) >> BSHIFT)         // 196 buckets
#define PAD 16                                        // 64B stride for global counters
#define TPB 256
#define EPT 16
#define TILE (TPB * EPT)                              // 4096 edges per block
#define NWG_E ((N_EDGES + TILE - 1) / TILE)           // 391
#define RPW 8                                         // rows per wave in gemm

// ---------------- CSR build: two-level counting sort by dst ----------------

__global__ __launch_bounds__(TPB) void k_bhist(const int* __restrict__ dst,
                                               int* __restrict__ gbh) {
    __shared__ int hist[NB];
    int t = threadIdx.x;
    for (int i = t; i < NB; i += TPB) hist[i] = 0;
    __syncthreads();
    int base = blockIdx.x * TILE;
#pragma unroll
    for (int j = 0; j < EPT; j++) {
        int i = base + j * TPB + t;
        if (i < N_EDGES) atomicAdd(&hist[dst[i] >> BSHIFT], 1);
    }
    __syncthreads();
    for (int i = t; i < NB; i += TPB)
        if (hist[i]) atomicAdd(&gbh[i * PAD], hist[i]);
}

__global__ __launch_bounds__(256) void k_scan_nb(const int* __restrict__ gbh,
                                                 int* __restrict__ bbase,
                                                 int* __restrict__ bcur) {
    __shared__ int lds[256];
    int t = threadIdx.x;
    int v = (t < NB) ? gbh[t * PAD] : 0;
    lds[t] = v;
    __syncthreads();
    for (int s = 1; s < 256; s <<= 1) {
        int a = (t >= s) ? lds[t - s] : 0;
        __syncthreads();
        lds[t] += a;
        __syncthreads();
    }
    int excl = lds[t] - v;
    if (t < NB) { bbase[t] = excl; bcur[t * PAD] = excl; }
    if (t == 0) bbase[NB] = N_EDGES;
}

__global__ __launch_bounds__(TPB) void k_bscatter(const int* __restrict__ src,
                                                  const int* __restrict__ dst,
                                                  int* __restrict__ bcur,
                                                  unsigned* __restrict__ ebuf) {
    __shared__ int hist[NB];
    __shared__ int lbase[NB];
    int t = threadIdx.x;
    for (int i = t; i < NB; i += TPB) hist[i] = 0;
    __syncthreads();
    int base = blockIdx.x * TILE;
#pragma unroll
    for (int j = 0; j < EPT; j++) {
        int i = base + j * TPB + t;
        if (i < N_EDGES) atomicAdd(&hist[dst[i] >> BSHIFT], 1);
    }
    __syncthreads();
    for (int i = t; i < NB; i += TPB) {
        int h = hist[i];
        lbase[i] = h ? atomicAdd(&bcur[i * PAD], h) : 0;
        hist[i] = 0;                       // reuse as local cursor
    }
    __syncthreads();
#pragma unroll
    for (int j = 0; j < EPT; j++) {
        int i = base + j * TPB + t;
        if (i < N_EDGES) {
            int d = dst[i];
            int b = d >> BSHIFT;
            int r = atomicAdd(&hist[b], 1);      // LDS atomic
            ebuf[lbase[b] + r] = (unsigned)src[i] | ((unsigned)(d & (BSIZE - 1)) << 17);
        }
    }
}

__global__ __launch_bounds__(TPB) void k_bcsr(const int* __restrict__ bbase,
                                              const unsigned* __restrict__ ebuf,
                                              int* __restrict__ off,
                                              int* __restrict__ csr) {
    __shared__ int dh[BSIZE];   // hist, then cursor
    __shared__ int dl[BSIZE];   // local exclusive scan
    __shared__ int tsum[TPB];
    int b = blockIdx.x;
    int t = threadIdx.x;
    int beg = bbase[b], end = bbase[b + 1];
    dh[t] = 0; dh[t + TPB] = 0;
    __syncthreads();
    for (int i = beg + t; i < end; i += TPB)
        atomicAdd(&dh[(ebuf[i] >> 17) & (BSIZE - 1)], 1);
    __syncthreads();
    int v0 = dh[2 * t], v1 = dh[2 * t + 1];
    tsum[t] = v0 + v1;
    __syncthreads();
    for (int s = 1; s < 256; s <<= 1) {
        int a = (t >= s) ? tsum[t - s] : 0;
        __syncthreads();
        tsum[t] += a;
        __syncthreads();
    }
    int excl = tsum[t] - (v0 + v1);
    dl[2 * t] = excl;
    dl[2 * t + 1] = excl + v0;
    int gd = (b << BSHIFT) + 2 * t;
    if (gd < N_NODES) off[gd] = beg + excl;
    if (gd + 1 < N_NODES) off[gd + 1] = beg + excl + v0;
    if (b == 0 && t == 0) off[N_NODES] = N_EDGES;
    dh[2 * t] = 0; dh[2 * t + 1] = 0;       // reset cursors
    __syncthreads();
    for (int i = beg + t; i < end; i += TPB) {
        unsigned pk = ebuf[i];
        int ld = (pk >> 17) & (BSIZE - 1);
        int r = atomicAdd(&dh[ld], 1);      // LDS atomic
        csr[beg + dl[ld] + r] = (int)(pk & 0x1FFFFu);
    }
}

// ---------------- per-layer kernels ----------------

// Precompute wv = [W1@att_src1, W1@att_dst1, W2@att_src2, W2@att_dst2] (4x64).
// Uses a_s[h] = h . att = x . (W @ att): moves the cross-lane reduction out
// of the hot GEMM entirely.
__global__ __launch_bounds__(256) void k_wvec(
    const float* __restrict__ W1, const float* __restrict__ as1,
    const float* __restrict__ ad1, const float* __restrict__ W2,
    const float* __restrict__ as2, const float* __restrict__ ad2,
    float* __restrict__ wv) {
    int w = threadIdx.x >> 6, lane = threadIdx.x & 63;
    const float* W  = (w < 2) ? W1 : W2;
    const float* av = (w == 0) ? as1 : (w == 1) ? ad1 : (w == 2) ? as2 : ad2;
    const float4* Wr = (const float4*)(W + lane * D);
    const float4* a4 = (const float4*)av;
    float acc0 = 0.f, acc1 = 0.f;
#pragma unroll
    for (int c = 0; c < D / 8; c++) {
        float4 w0 = Wr[2 * c], w1 = Wr[2 * c + 1];
        float4 v0 = a4[2 * c], v1 = a4[2 * c + 1];
        acc0 += w0.x * v0.x + w0.y * v0.y + w0.z * v0.z + w0.w * v0.w;
        acc1 += w1.x * v1.x + w1.y * v1.y + w1.z * v1.z + w1.w * v1.w;
    }
    wv[w * D + lane] = acc0 + acc1;
}

// h = x @ W ; a_s = x . wsv ; a_d = x . wdv
// One wave = RPW consecutive rows, processed in pairs -> 6 independent fma
// chains per k-step. Lane holds W column `lane` in regs. x read as broadcast
// float4; a_s/a_d accumulate lane-redundantly (no shfl anywhere).
__global__ __launch_bounds__(256) void k_gemm_attn(
    const float* __restrict__ x, const float* __restrict__ W,
    const float* __restrict__ wv,   // [wsv | wdv]
    float* __restrict__ h, float* __restrict__ a_s, float* __restrict__ a_d) {
    __shared__ float4 wvs[D / 4], wvd[D / 4];
    int t = threadIdx.x;
    if (t < D / 4) wvs[t] = ((const float4*)wv)[t];
    else if (t < D / 2) wvd[t - D / 4] = ((const float4*)(wv + D))[t - D / 4];
    int lane = t & 63;
    float wl[D];
#pragma unroll
    for (int k = 0; k < D; k++) wl[k] = W[k * D + lane];   // coalesced
    __syncthreads();
    int wid = blockIdx.x * 4 + (t >> 6);
    int r0 = wid * RPW;                      // grid sized exactly
    const float4* xr = (const float4*)(x + (size_t)r0 * D);
    for (int rp = 0; rp < RPW; rp += 2) {
        float h0 = 0.f, h1 = 0.f, s0 = 0.f, s1 = 0.f, e0 = 0.f, e1 = 0.f;
#pragma unroll
        for (int k4 = 0; k4 < D / 4; k4++) {
            float4 xv0 = xr[rp * (D / 4) + k4];        // broadcast
            float4 xv1 = xr[(rp + 1) * (D / 4) + k4];
            float4 ws4 = wvs[k4];                      // LDS broadcast
            float4 wd4 = wvd[k4];
            h0 = fmaf(xv0.x, wl[4 * k4 + 0], h0);
            h0 = fmaf(xv0.y, wl[4 * k4 + 1], h0);
            h0 = fmaf(xv0.z, wl[4 * k4 + 2], h0);
            h0 = fmaf(xv0.w, wl[4 * k4 + 3], h0);
            h1 = fmaf(xv1.x, wl[4 * k4 + 0], h1);
            h1 = fmaf(xv1.y, wl[4 * k4 + 1], h1);
            h1 = fmaf(xv1.z, wl[4 * k4 + 2], h1);
            h1 = fmaf(xv1.w, wl[4 * k4 + 3], h1);
            s0 = fmaf(xv0.x, ws4.x, s0); s0 = fmaf(xv0.y, ws4.y, s0);
            s0 = fmaf(xv0.z, ws4.z, s0); s0 = fmaf(xv0.w, ws4.w, s0);
            s1 = fmaf(xv1.x, ws4.x, s1); s1 = fmaf(xv1.y, ws4.y, s1);
            s1 = fmaf(xv1.z, ws4.z, s1); s1 = fmaf(xv1.w, ws4.w, s1);
            e0 = fmaf(xv0.x, wd4.x, e0); e0 = fmaf(xv0.y, wd4.y, e0);
            e0 = fmaf(xv0.z, wd4.z, e0); e0 = fmaf(xv0.w, wd4.w, e0);
            e1 = fmaf(xv1.x, wd4.x, e1); e1 = fmaf(xv1.y, wd4.y, e1);
            e1 = fmaf(xv1.z, wd4.z, e1); e1 = fmaf(xv1.w, wd4.w, e1);
        }
        h[(size_t)(r0 + rp) * D + lane] = h0;          // coalesced
        h[(size_t)(r0 + rp + 1) * D + lane] = h1;
        if (lane == 0) {
            a_s[r0 + rp] = s0; a_s[r0 + rp + 1] = s1;
            a_d[r0 + rp] = e0; a_d[r0 + rp + 1] = e1;
        }
    }
}

// one wave per dst node. Weight phase: lane = edge (64-edge chunks).
// Gather phase: group g = lane>>4 picks the edge, q = lane&15 picks float4.
__global__ __launch_bounds__(256) void k_aggr(
    const int* __restrict__ off, const int* __restrict__ csr,
    const float* __restrict__ h, const float* __restrict__ a_s,
    const float* __restrict__ a_d, const float* __restrict__ bias,
    float* __restrict__ out, int do_relu) {
    int node = (blockIdx.x * blockDim.x + threadIdx.x) >> 6;
    int lane = threadIdx.x & 63;
    if (node >= N_NODES) return;
    int g = lane >> 4, q = lane & 15;
    int beg = off[node], end = off[node + 1];
    float ad = a_d[node];
    float s = 0.f;
    float4 acc = {0.f, 0.f, 0.f, 0.f};
    for (int c = beg; c < end; c += 64) {
        int idx = c + lane;
        int sv = 0;
        float w = 0.f;
        if (idx < end) {
            sv = csr[idx];
            float tv = a_s[sv] + ad;
            tv = fmaxf(tv, NEG_SLOPE * tv);  // leaky_relu, slope<1
            w = __expf(tv);                  // softmax shift dropped (|e| small)
        }
        float ws = w;
#pragma unroll
        for (int sft = 32; sft > 0; sft >>= 1) ws += __shfl_xor(ws, sft);
        s += ws;
        int cnt = min(end - c, 64);
        int iters = (cnt + 3) >> 2;
        for (int i = 0; i < iters; i++) {
            int j = i * 4 + g;               // w==0 for tail edges -> safe
            float wj = __shfl(w, j);
            int svj = __shfl(sv, j);
            float4 hv = ((const float4*)(h + (size_t)svj * D))[q];
            acc.x = fmaf(wj, hv.x, acc.x);
            acc.y = fmaf(wj, hv.y, acc.y);
            acc.z = fmaf(wj, hv.z, acc.z);
            acc.w = fmaf(wj, hv.w, acc.w);
        }
    }
#pragma unroll
    for (int sft = 16; sft <= 32; sft <<= 1) {
        acc.x += __shfl_xor(acc.x, sft);
        acc.y += __shfl_xor(acc.y, sft);
        acc.z += __shfl_xor(acc.z, sft);
        acc.w += __shfl_xor(acc.w, sft);
    }
    if (g == 0) {
        float inv = 1.f / (s + SM_EPS);
        float4 b4 = ((const float4*)bias)[q];
        float4 o;
        o.x = fmaf(acc.x, inv, b4.x);
        o.y = fmaf(acc.y, inv, b4.y);
        o.z = fmaf(acc.z, inv, b4.z);
        o.w = fmaf(acc.w, inv, b4.w);
        if (do_relu) {
            o.x = fmaxf(o.x, 0.f); o.y = fmaxf(o.y, 0.f);
            o.z = fmaxf(o.z, 0.f); o.w = fmaxf(o.w, 0.f);
        }
        ((float4*)(out + (size_t)node * D))[q] = o;
    }
}

// ---------------- launch ----------------

extern "C" void kernel_launch(void* const* d_in, const int* in_sizes, int n_in,
                              void* d_out, int out_size, void* d_ws, size_t ws_size,
                              hipStream_t stream) {
    const float* x   = (const float*)d_in[0];
    const int*   ei  = (const int*)d_in[1];
    const float* W1  = (const float*)d_in[2];
    const float* as1 = (const float*)d_in[3];
    const float* ad1 = (const float*)d_in[4];
    const float* b1  = (const float*)d_in[5];
    const float* W2  = (const float*)d_in[6];
    const float* as2 = (const float*)d_in[7];
    const float* ad2 = (const float*)d_in[8];
    const float* b2  = (const float*)d_in[9];
    float* out = (float*)d_out;

    const int* src = ei;
    const int* dst = ei + N_EDGES;

    char* ws = (char*)d_ws;
    size_t o = 0;
    auto alloc = [&](size_t bytes) { void* p = ws + o; o += (bytes + 255) & ~255ull; return p; };
    float* h     = (float*)alloc((size_t)N_NODES * D * sizeof(float));  // 25.6 MB
    float* a_s   = (float*)alloc(N_NODES * sizeof(float));
    float* a_d   = (float*)alloc(N_NODES * sizeof(float));
    int*   off   = (int*)alloc((N_NODES + 1) * sizeof(int));
    int*   csr   = (int*)alloc(N_EDGES * sizeof(int));                  // 6.4 MB
    int*   gbh   = (int*)alloc(NB * PAD * sizeof(int));
    int*   bbase = (int*)alloc((NB + 1) * sizeof(int));
    int*   bcur  = (int*)alloc(NB * PAD * sizeof(int));
    float* wv    = (float*)alloc(4 * D * sizeof(float));
    // ebuf aliases h: CSR build completes before k_gemm_attn writes h
    unsigned* ebuf = (unsigned*)h;                                      // 6.4 MB < 25.6 MB

    // ---- precompute W@att vectors (both layers) ----
    k_wvec<<<1, 256, 0, stream>>>(W1, as1, ad1, W2, as2, ad2, wv);

    // ---- CSR by dst (two-level counting sort; shared by both layers) ----
    hipMemsetAsync(gbh, 0, NB * PAD * sizeof(int), stream);
    k_bhist   <<<NWG_E, TPB, 0, stream>>>(dst, gbh);
    k_scan_nb <<<1, 256, 0, stream>>>(gbh, bbase, bcur);
    k_bscatter<<<NWG_E, TPB, 0, stream>>>(src, dst, bcur, ebuf);
    k_bcsr    <<<NB, TPB, 0, stream>>>(bbase, ebuf, off, csr);

    // ---- layer 1: x -> out (relu'd) ----
    int gemm_grid = N_NODES / (4 * RPW);   // 3125 exact
    k_gemm_attn<<<gemm_grid, 256, 0, stream>>>(x, W1, wv, h, a_s, a_d);
    k_aggr     <<<N_NODES / 4, 256, 0, stream>>>(off, csr, h, a_s, a_d, b1, out, 1);

    // ---- layer 2: out -> out ----
    k_gemm_attn<<<gemm_grid, 256, 0, stream>>>(out, W2, wv + 2 * D, h, a_s, a_d);
    k_aggr     <<<N_NODES / 4, 256, 0, stream>>>(off, csr, h, a_s, a_d, b2, out, 0);
}

// Round 5
// 347.130 us; speedup vs baseline: 1.4713x; 1.4713x over previous
//
#include <hip/hip_runtime.h>

#define N_NODES 100000
#define N_EDGES 1600000
#define D 64
#define NEG_SLOPE 0.2f
#define SM_EPS 1e-16f

#define BSHIFT 9
#define BSIZE (1 << BSHIFT)                          // 512 dsts per bucket
#define NB ((N_NODES + BSIZE - 1) >> BSHIFT)         // 196 buckets
#define PAD 16                                        // 64B stride for global counters
#define TPB 256
#define EPT 16
#define TILE (TPB * EPT)                              // 4096 edges per block
#define NWG_E ((N_EDGES + TILE - 1) / TILE)           // 391

#define GEMM_RR 8                                     // rows per thread
#define GEMM_ROWS 128                                 // rows per block (16 groups x 8)
#define NWG_GEMM ((N_NODES + GEMM_ROWS - 1) / GEMM_ROWS)  // 782

#define COMP(v, kk) ((kk) == 0 ? (v).x : (kk) == 1 ? (v).y : (kk) == 2 ? (v).z : (v).w)

// ---------------- CSR build: two-level counting sort by dst ----------------

__global__ __launch_bounds__(TPB) void k_bhist(const int* __restrict__ dst,
                                               int* __restrict__ gbh) {
    __shared__ int hist[NB];
    int t = threadIdx.x;
    for (int i = t; i < NB; i += TPB) hist[i] = 0;
    __syncthreads();
    int base = blockIdx.x * TILE;
#pragma unroll
    for (int j = 0; j < EPT; j++) {
        int i = base + j * TPB + t;
        if (i < N_EDGES) atomicAdd(&hist[dst[i] >> BSHIFT], 1);
    }
    __syncthreads();
    for (int i = t; i < NB; i += TPB)
        if (hist[i]) atomicAdd(&gbh[i * PAD], hist[i]);
}

__global__ __launch_bounds__(256) void k_scan_nb(const int* __restrict__ gbh,
                                                 int* __restrict__ bbase,
                                                 int* __restrict__ bcur) {
    __shared__ int lds[256];
    int t = threadIdx.x;
    int v = (t < NB) ? gbh[t * PAD] : 0;
    lds[t] = v;
    __syncthreads();
    for (int s = 1; s < 256; s <<= 1) {
        int a = (t >= s) ? lds[t - s] : 0;
        __syncthreads();
        lds[t] += a;
        __syncthreads();
    }
    int excl = lds[t] - v;
    if (t < NB) { bbase[t] = excl; bcur[t * PAD] = excl; }
    if (t == 0) bbase[NB] = N_EDGES;
}

__global__ __launch_bounds__(TPB) void k_bscatter(const int* __restrict__ src,
                                                  const int* __restrict__ dst,
                                                  int* __restrict__ bcur,
                                                  unsigned* __restrict__ ebuf) {
    __shared__ int hist[NB];
    __shared__ int lbase[NB];
    int t = threadIdx.x;
    for (int i = t; i < NB; i += TPB) hist[i] = 0;
    __syncthreads();
    int base = blockIdx.x * TILE;
#pragma unroll
    for (int j = 0; j < EPT; j++) {
        int i = base + j * TPB + t;
        if (i < N_EDGES) atomicAdd(&hist[dst[i] >> BSHIFT], 1);
    }
    __syncthreads();
    for (int i = t; i < NB; i += TPB) {
        int h = hist[i];
        lbase[i] = h ? atomicAdd(&bcur[i * PAD], h) : 0;
        hist[i] = 0;                       // reuse as local cursor
    }
    __syncthreads();
#pragma unroll
    for (int j = 0; j < EPT; j++) {
        int i = base + j * TPB + t;
        if (i < N_EDGES) {
            int d = dst[i];
            int b = d >> BSHIFT;
            int r = atomicAdd(&hist[b], 1);      // LDS atomic
            ebuf[lbase[b] + r] = (unsigned)src[i] | ((unsigned)(d & (BSIZE - 1)) << 17);
        }
    }
}

__global__ __launch_bounds__(TPB) void k_bcsr(const int* __restrict__ bbase,
                                              const unsigned* __restrict__ ebuf,
                                              int* __restrict__ off,
                                              int* __restrict__ csr) {
    __shared__ int dh[BSIZE];   // hist, then cursor
    __shared__ int dl[BSIZE];   // local exclusive scan
    __shared__ int tsum[TPB];
    int b = blockIdx.x;
    int t = threadIdx.x;
    int beg = bbase[b], end = bbase[b + 1];
    dh[t] = 0; dh[t + TPB] = 0;
    __syncthreads();
    for (int i = beg + t; i < end; i += TPB)
        atomicAdd(&dh[(ebuf[i] >> 17) & (BSIZE - 1)], 1);
    __syncthreads();
    int v0 = dh[2 * t], v1 = dh[2 * t + 1];
    tsum[t] = v0 + v1;
    __syncthreads();
    for (int s = 1; s < 256; s <<= 1) {
        int a = (t >= s) ? tsum[t - s] : 0;
        __syncthreads();
        tsum[t] += a;
        __syncthreads();
    }
    int excl = tsum[t] - (v0 + v1);
    dl[2 * t] = excl;
    dl[2 * t + 1] = excl + v0;
    int gd = (b << BSHIFT) + 2 * t;
    if (gd < N_NODES) off[gd] = beg + excl;
    if (gd + 1 < N_NODES) off[gd + 1] = beg + excl + v0;
    if (b == 0 && t == 0) off[N_NODES] = N_EDGES;
    dh[2 * t] = 0; dh[2 * t + 1] = 0;       // reset cursors
    __syncthreads();
    for (int i = beg + t; i < end; i += TPB) {
        unsigned pk = ebuf[i];
        int ld = (pk >> 17) & (BSIZE - 1);
        int r = atomicAdd(&dh[ld], 1);      // LDS atomic
        csr[beg + dl[ld] + r] = (int)(pk & 0x1FFFFu);
    }
}

// ---------------- per-layer kernels ----------------

// Precompute wv = [W1@att_src1, W1@att_dst1, W2@att_src2, W2@att_dst2] (4x64).
__global__ __launch_bounds__(256) void k_wvec(
    const float* __restrict__ W1, const float* __restrict__ as1,
    const float* __restrict__ ad1, const float* __restrict__ W2,
    const float* __restrict__ as2, const float* __restrict__ ad2,
    float* __restrict__ wv) {
    int w = threadIdx.x >> 6, lane = threadIdx.x & 63;
    const float* W  = (w < 2) ? W1 : W2;
    const float* av = (w == 0) ? as1 : (w == 1) ? ad1 : (w == 2) ? as2 : ad2;
    const float4* Wr = (const float4*)(W + lane * D);
    const float4* a4 = (const float4*)av;
    float acc0 = 0.f, acc1 = 0.f;
#pragma unroll
    for (int c = 0; c < D / 8; c++) {
        float4 w0 = Wr[2 * c], w1 = Wr[2 * c + 1];
        float4 v0 = a4[2 * c], v1 = a4[2 * c + 1];
        acc0 += w0.x * v0.x + w0.y * v0.y + w0.z * v0.z + w0.w * v0.w;
        acc1 += w1.x * v1.x + w1.y * v1.y + w1.z * v1.z + w1.w * v1.w;
    }
    wv[w * D + lane] = acc0 + acc1;
}

// a_s = x . wsv ; a_d = x . wdv — one thread per row. Lines (4 float4 of the
// same row) are fully consumed across k4 iterations -> traffic = |x| exactly.
__global__ __launch_bounds__(256) void k_attn(
    const float* __restrict__ x, const float* __restrict__ wv,
    float* __restrict__ a_s, float* __restrict__ a_d) {
    __shared__ float4 wvs[D / 4], wvd[D / 4];
    int t = threadIdx.x;
    if (t < D / 4) wvs[t] = ((const float4*)wv)[t];
    else if (t < D / 2) wvd[t - D / 4] = ((const float4*)(wv + D))[t - D / 4];
    __syncthreads();
    int r = blockIdx.x * 256 + t;
    if (r >= N_NODES) return;
    const float4* x4 = (const float4*)(x + (size_t)r * D);
    float s = 0.f, e = 0.f;
#pragma unroll
    for (int k4 = 0; k4 < D / 4; k4++) {
        float4 xv = x4[k4];
        float4 a = wvs[k4], b = wvd[k4];
        s += xv.x * a.x + xv.y * a.y + xv.z * a.z + xv.w * a.w;
        e += xv.x * b.x + xv.y * b.y + xv.z * b.z + xv.w * b.w;
    }
    a_s[r] = s;
    a_d[r] = e;
}

// h = x @ W. W in LDS (16 KB); thread (g=t>>4, q=t&15) computes an 8-row x
// 4-col register tile. x read as broadcast float4 (16 lanes share a row).
// ~90 VGPR -> high occupancy; zero shfl; 32 independent fma chains.
__global__ __launch_bounds__(256) void k_gemm(
    const float* __restrict__ x, const float* __restrict__ W,
    float* __restrict__ h) {
    __shared__ float4 Wl4[D * D / 4];                 // 16 KB
    int t = threadIdx.x;
    const float4* W4 = (const float4*)W;
#pragma unroll
    for (int i = 0; i < 4; i++) Wl4[i * 256 + t] = W4[i * 256 + t];
    __syncthreads();
    int q = t & 15;
    int r0 = blockIdx.x * GEMM_ROWS + (t >> 4) * GEMM_RR;
    const float4* x4 = (const float4*)x;
    float4 acc[GEMM_RR];
#pragma unroll
    for (int j = 0; j < GEMM_RR; j++) acc[j] = {0.f, 0.f, 0.f, 0.f};
    for (int k4 = 0; k4 < D / 4; k4++) {
        float4 xv[GEMM_RR];
#pragma unroll
        for (int j = 0; j < GEMM_RR; j++) {
            int r = r0 + j;
            r = (r < N_NODES) ? r : N_NODES - 1;       // clamp (tail block)
            xv[j] = x4[(size_t)r * (D / 4) + k4];      // broadcast across 16 lanes
        }
#pragma unroll
        for (int kk = 0; kk < 4; kk++) {
            float4 w4 = Wl4[(k4 * 4 + kk) * 16 + q];
#pragma unroll
            for (int j = 0; j < GEMM_RR; j++) {
                float xs = COMP(xv[j], kk);
                acc[j].x = fmaf(xs, w4.x, acc[j].x);
                acc[j].y = fmaf(xs, w4.y, acc[j].y);
                acc[j].z = fmaf(xs, w4.z, acc[j].z);
                acc[j].w = fmaf(xs, w4.w, acc[j].w);
            }
        }
    }
    float4* h4 = (float4*)h;
#pragma unroll
    for (int j = 0; j < GEMM_RR; j++) {
        int r = r0 + j;
        if (r < N_NODES) h4[(size_t)r * (D / 4) + q] = acc[j];
    }
}

// one wave per dst node. Weight phase: lane = edge (64-edge chunks).
// Gather phase: group g = lane>>4 picks the edge, q = lane&15 picks float4.
__global__ __launch_bounds__(256) void k_aggr(
    const int* __restrict__ off, const int* __restrict__ csr,
    const float* __restrict__ h, const float* __restrict__ a_s,
    const float* __restrict__ a_d, const float* __restrict__ bias,
    float* __restrict__ out, int do_relu) {
    int node = (blockIdx.x * blockDim.x + threadIdx.x) >> 6;
    int lane = threadIdx.x & 63;
    if (node >= N_NODES) return;
    int g = lane >> 4, q = lane & 15;
    int beg = off[node], end = off[node + 1];
    float ad = a_d[node];
    float s = 0.f;
    float4 acc = {0.f, 0.f, 0.f, 0.f};
    for (int c = beg; c < end; c += 64) {
        int idx = c + lane;
        int sv = 0;
        float w = 0.f;
        if (idx < end) {
            sv = csr[idx];
            float tv = a_s[sv] + ad;
            tv = fmaxf(tv, NEG_SLOPE * tv);  // leaky_relu, slope<1
            w = __expf(tv);                  // softmax shift dropped (|e| small)
        }
        float ws = w;
#pragma unroll
        for (int sft = 32; sft > 0; sft >>= 1) ws += __shfl_xor(ws, sft);
        s += ws;
        int cnt = min(end - c, 64);
        int iters = (cnt + 3) >> 2;
        for (int i = 0; i < iters; i++) {
            int j = i * 4 + g;               // w==0 for tail edges -> safe
            float wj = __shfl(w, j);
            int svj = __shfl(sv, j);
            float4 hv = ((const float4*)(h + (size_t)svj * D))[q];
            acc.x = fmaf(wj, hv.x, acc.x);
            acc.y = fmaf(wj, hv.y, acc.y);
            acc.z = fmaf(wj, hv.z, acc.z);
            acc.w = fmaf(wj, hv.w, acc.w);
        }
    }
#pragma unroll
    for (int sft = 16; sft <= 32; sft <<= 1) {
        acc.x += __shfl_xor(acc.x, sft);
        acc.y += __shfl_xor(acc.y, sft);
        acc.z += __shfl_xor(acc.z, sft);
        acc.w += __shfl_xor(acc.w, sft);
    }
    if (g == 0) {
        float inv = 1.f / (s + SM_EPS);
        float4 b4 = ((const float4*)bias)[q];
        float4 o;
        o.x = fmaf(acc.x, inv, b4.x);
        o.y = fmaf(acc.y, inv, b4.y);
        o.z = fmaf(acc.z, inv, b4.z);
        o.w = fmaf(acc.w, inv, b4.w);
        if (do_relu) {
            o.x = fmaxf(o.x, 0.f); o.y = fmaxf(o.y, 0.f);
            o.z = fmaxf(o.z, 0.f); o.w = fmaxf(o.w, 0.f);
        }
        ((float4*)(out + (size_t)node * D))[q] = o;
    }
}

// ---------------- launch ----------------

extern "C" void kernel_launch(void* const* d_in, const int* in_sizes, int n_in,
                              void* d_out, int out_size, void* d_ws, size_t ws_size,
                              hipStream_t stream) {
    const float* x   = (const float*)d_in[0];
    const int*   ei  = (const int*)d_in[1];
    const float* W1  = (const float*)d_in[2];
    const float* as1 = (const float*)d_in[3];
    const float* ad1 = (const float*)d_in[4];
    const float* b1  = (const float*)d_in[5];
    const float* W2  = (const float*)d_in[6];
    const float* as2 = (const float*)d_in[7];
    const float* ad2 = (const float*)d_in[8];
    const float* b2  = (const float*)d_in[9];
    float* out = (float*)d_out;

    const int* src = ei;
    const int* dst = ei + N_EDGES;

    char* ws = (char*)d_ws;
    size_t o = 0;
    auto alloc = [&](size_t bytes) { void* p = ws + o; o += (bytes + 255) & ~255ull; return p; };
    float* h     = (float*)alloc((size_t)N_NODES * D * sizeof(float));  // 25.6 MB
    float* a_s   = (float*)alloc(N_NODES * sizeof(float));
    float* a_d   = (float*)alloc(N_NODES * sizeof(float));
    int*   off   = (int*)alloc((N_NODES + 1) * sizeof(int));
    int*   csr   = (int*)alloc(N_EDGES * sizeof(int));                  // 6.4 MB
    int*   gbh   = (int*)alloc(NB * PAD * sizeof(int));
    int*   bbase = (int*)alloc((NB + 1) * sizeof(int));
    int*   bcur  = (int*)alloc(NB * PAD * sizeof(int));
    float* wv    = (float*)alloc(4 * D * sizeof(float));
    // ebuf aliases h: CSR build completes before k_gemm writes h
    unsigned* ebuf = (unsigned*)h;                                      // 6.4 MB < 25.6 MB

    // ---- precompute W@att vectors (both layers) ----
    k_wvec<<<1, 256, 0, stream>>>(W1, as1, ad1, W2, as2, ad2, wv);

    // ---- CSR by dst (two-level counting sort; shared by both layers) ----
    hipMemsetAsync(gbh, 0, NB * PAD * sizeof(int), stream);
    k_bhist   <<<NWG_E, TPB, 0, stream>>>(dst, gbh);
    k_scan_nb <<<1, 256, 0, stream>>>(gbh, bbase, bcur);
    k_bscatter<<<NWG_E, TPB, 0, stream>>>(src, dst, bcur, ebuf);
    k_bcsr    <<<NB, TPB, 0, stream>>>(bbase, ebuf, off, csr);

    // ---- layer 1: x -> out (relu'd) ----
    k_attn<<<(N_NODES + 255) / 256, 256, 0, stream>>>(x, wv, a_s, a_d);
    k_gemm<<<NWG_GEMM, 256, 0, stream>>>(x, W1, h);
    k_aggr<<<N_NODES / 4, 256, 0, stream>>>(off, csr, h, a_s, a_d, b1, out, 1);

    // ---- layer 2: out -> out ----
    k_attn<<<(N_NODES + 255) / 256, 256, 0, stream>>>(out, wv + 2 * D, a_s, a_d);
    k_gemm<<<NWG_GEMM, 256, 0, stream>>>(out, W2, h);
    k_aggr<<<N_NODES / 4, 256, 0, stream>>>(off, csr, h, a_s, a_d, b2, out, 0);
}

// Round 6
// 321.758 us; speedup vs baseline: 1.5874x; 1.0789x over previous
//
#include <hip/hip_runtime.h>

#define N_NODES 100000
#define N_EDGES 1600000
#define D 64
#define NEG_SLOPE 0.2f
#define SM_EPS 1e-16f

#define BSHIFT 9
#define BSIZE (1 << BSHIFT)                          // 512 dsts per bucket
#define NB ((N_NODES + BSIZE - 1) >> BSHIFT)         // 196 buckets
#define PAD 16                                        // 64B stride for global counters
#define TPB 256
#define EPT 16
#define TILE (TPB * EPT)                              // 4096 edges per block
#define NWG_E ((N_EDGES + TILE - 1) / TILE)           // 391

#define GEMM_RR 8                                     // rows per thread
#define GEMM_ROWS 128                                 // rows per block (16 groups x 8)
#define NWG_GEMM ((N_NODES + GEMM_ROWS - 1) / GEMM_ROWS)  // 782

#define COMP(v, kk) ((kk) == 0 ? (v).x : (kk) == 1 ? (v).y : (kk) == 2 ? (v).z : (v).w)

typedef _Float16 half4_t __attribute__((ext_vector_type(4)));   // 8 B

// ---------------- CSR build: two-level counting sort by dst ----------------

__global__ __launch_bounds__(TPB) void k_bhist(const int* __restrict__ dst,
                                               int* __restrict__ gbh) {
    __shared__ int hist[NB];
    int t = threadIdx.x;
    for (int i = t; i < NB; i += TPB) hist[i] = 0;
    __syncthreads();
    int base = blockIdx.x * TILE;
#pragma unroll
    for (int j = 0; j < EPT; j++) {
        int i = base + j * TPB + t;
        if (i < N_EDGES) atomicAdd(&hist[dst[i] >> BSHIFT], 1);
    }
    __syncthreads();
    for (int i = t; i < NB; i += TPB)
        if (hist[i]) atomicAdd(&gbh[i * PAD], hist[i]);
}

__global__ __launch_bounds__(256) void k_scan_nb(const int* __restrict__ gbh,
                                                 int* __restrict__ bbase,
                                                 int* __restrict__ bcur) {
    __shared__ int lds[256];
    int t = threadIdx.x;
    int v = (t < NB) ? gbh[t * PAD] : 0;
    lds[t] = v;
    __syncthreads();
    for (int s = 1; s < 256; s <<= 1) {
        int a = (t >= s) ? lds[t - s] : 0;
        __syncthreads();
        lds[t] += a;
        __syncthreads();
    }
    int excl = lds[t] - v;
    if (t < NB) { bbase[t] = excl; bcur[t * PAD] = excl; }
    if (t == 0) bbase[NB] = N_EDGES;
}

__global__ __launch_bounds__(TPB) void k_bscatter(const int* __restrict__ src,
                                                  const int* __restrict__ dst,
                                                  int* __restrict__ bcur,
                                                  unsigned* __restrict__ ebuf) {
    __shared__ int hist[NB];
    __shared__ int lbase[NB];
    int t = threadIdx.x;
    for (int i = t; i < NB; i += TPB) hist[i] = 0;
    __syncthreads();
    int base = blockIdx.x * TILE;
#pragma unroll
    for (int j = 0; j < EPT; j++) {
        int i = base + j * TPB + t;
        if (i < N_EDGES) atomicAdd(&hist[dst[i] >> BSHIFT], 1);
    }
    __syncthreads();
    for (int i = t; i < NB; i += TPB) {
        int h = hist[i];
        lbase[i] = h ? atomicAdd(&bcur[i * PAD], h) : 0;
        hist[i] = 0;                       // reuse as local cursor
    }
    __syncthreads();
#pragma unroll
    for (int j = 0; j < EPT; j++) {
        int i = base + j * TPB + t;
        if (i < N_EDGES) {
            int d = dst[i];
            int b = d >> BSHIFT;
            int r = atomicAdd(&hist[b], 1);      // LDS atomic
            ebuf[lbase[b] + r] = (unsigned)src[i] | ((unsigned)(d & (BSIZE - 1)) << 17);
        }
    }
}

__global__ __launch_bounds__(TPB) void k_bcsr(const int* __restrict__ bbase,
                                              const unsigned* __restrict__ ebuf,
                                              int* __restrict__ off,
                                              int* __restrict__ csr) {
    __shared__ int dh[BSIZE];   // hist, then cursor
    __shared__ int dl[BSIZE];   // local exclusive scan
    __shared__ int tsum[TPB];
    int b = blockIdx.x;
    int t = threadIdx.x;
    int beg = bbase[b], end = bbase[b + 1];
    dh[t] = 0; dh[t + TPB] = 0;
    __syncthreads();
    for (int i = beg + t; i < end; i += TPB)
        atomicAdd(&dh[(ebuf[i] >> 17) & (BSIZE - 1)], 1);
    __syncthreads();
    int v0 = dh[2 * t], v1 = dh[2 * t + 1];
    tsum[t] = v0 + v1;
    __syncthreads();
    for (int s = 1; s < 256; s <<= 1) {
        int a = (t >= s) ? tsum[t - s] : 0;
        __syncthreads();
        tsum[t] += a;
        __syncthreads();
    }
    int excl = tsum[t] - (v0 + v1);
    dl[2 * t] = excl;
    dl[2 * t + 1] = excl + v0;
    int gd = (b << BSHIFT) + 2 * t;
    if (gd < N_NODES) off[gd] = beg + excl;
    if (gd + 1 < N_NODES) off[gd + 1] = beg + excl + v0;
    if (b == 0 && t == 0) off[N_NODES] = N_EDGES;
    dh[2 * t] = 0; dh[2 * t + 1] = 0;       // reset cursors
    __syncthreads();
    for (int i = beg + t; i < end; i += TPB) {
        unsigned pk = ebuf[i];
        int ld = (pk >> 17) & (BSIZE - 1);
        int r = atomicAdd(&dh[ld], 1);      // LDS atomic
        csr[beg + dl[ld] + r] = (int)(pk & 0x1FFFFu);
    }
}

// ---------------- per-layer kernels ----------------

// Precompute wv = [W1@att_src1, W1@att_dst1, W2@att_src2, W2@att_dst2] (4x64).
__global__ __launch_bounds__(256) void k_wvec(
    const float* __restrict__ W1, const float* __restrict__ as1,
    const float* __restrict__ ad1, const float* __restrict__ W2,
    const float* __restrict__ as2, const float* __restrict__ ad2,
    float* __restrict__ wv) {
    int w = threadIdx.x >> 6, lane = threadIdx.x & 63;
    const float* W  = (w < 2) ? W1 : W2;
    const float* av = (w == 0) ? as1 : (w == 1) ? ad1 : (w == 2) ? as2 : ad2;
    const float4* Wr = (const float4*)(W + lane * D);
    const float4* a4 = (const float4*)av;
    float acc0 = 0.f, acc1 = 0.f;
#pragma unroll
    for (int c = 0; c < D / 8; c++) {
        float4 w0 = Wr[2 * c], w1 = Wr[2 * c + 1];
        float4 v0 = a4[2 * c], v1 = a4[2 * c + 1];
        acc0 += w0.x * v0.x + w0.y * v0.y + w0.z * v0.z + w0.w * v0.w;
        acc1 += w1.x * v1.x + w1.y * v1.y + w1.z * v1.z + w1.w * v1.w;
    }
    wv[w * D + lane] = acc0 + acc1;
}

// a_s = x . wsv ; a_d = x . wdv — one thread per row.
__global__ __launch_bounds__(256) void k_attn(
    const float* __restrict__ x, const float* __restrict__ wv,
    float* __restrict__ a_s, float* __restrict__ a_d) {
    __shared__ float4 wvs[D / 4], wvd[D / 4];
    int t = threadIdx.x;
    if (t < D / 4) wvs[t] = ((const float4*)wv)[t];
    else if (t < D / 2) wvd[t - D / 4] = ((const float4*)(wv + D))[t - D / 4];
    __syncthreads();
    int r = blockIdx.x * 256 + t;
    if (r >= N_NODES) return;
    const float4* x4 = (const float4*)(x + (size_t)r * D);
    float s = 0.f, e = 0.f;
#pragma unroll
    for (int k4 = 0; k4 < D / 4; k4++) {
        float4 xv = x4[k4];
        float4 a = wvs[k4], b = wvd[k4];
        s += xv.x * a.x + xv.y * a.y + xv.z * a.z + xv.w * a.w;
        e += xv.x * b.x + xv.y * b.y + xv.z * b.z + xv.w * b.w;
    }
    a_s[r] = s;
    a_d[r] = e;
}

// h16 = fp16(x @ W). W in LDS; thread (g=t>>4, q=t&15) computes an 8-row x
// 4-col register tile. h stored fp16: halves the k_aggr gather footprint.
__global__ __launch_bounds__(256) void k_gemm(
    const float* __restrict__ x, const float* __restrict__ W,
    _Float16* __restrict__ h16) {
    __shared__ float4 Wl4[D * D / 4];                 // 16 KB
    int t = threadIdx.x;
    const float4* W4 = (const float4*)W;
#pragma unroll
    for (int i = 0; i < 4; i++) Wl4[i * 256 + t] = W4[i * 256 + t];
    __syncthreads();
    int q = t & 15;
    int r0 = blockIdx.x * GEMM_ROWS + (t >> 4) * GEMM_RR;
    const float4* x4 = (const float4*)x;
    float4 acc[GEMM_RR];
#pragma unroll
    for (int j = 0; j < GEMM_RR; j++) acc[j] = {0.f, 0.f, 0.f, 0.f};
    for (int k4 = 0; k4 < D / 4; k4++) {
        float4 xv[GEMM_RR];
#pragma unroll
        for (int j = 0; j < GEMM_RR; j++) {
            int r = r0 + j;
            r = (r < N_NODES) ? r : N_NODES - 1;       // clamp (tail block)
            xv[j] = x4[(size_t)r * (D / 4) + k4];      // broadcast across 16 lanes
        }
#pragma unroll
        for (int kk = 0; kk < 4; kk++) {
            float4 w4 = Wl4[(k4 * 4 + kk) * 16 + q];
#pragma unroll
            for (int j = 0; j < GEMM_RR; j++) {
                float xs = COMP(xv[j], kk);
                acc[j].x = fmaf(xs, w4.x, acc[j].x);
                acc[j].y = fmaf(xs, w4.y, acc[j].y);
                acc[j].z = fmaf(xs, w4.z, acc[j].z);
                acc[j].w = fmaf(xs, w4.w, acc[j].w);
            }
        }
    }
#pragma unroll
    for (int j = 0; j < GEMM_RR; j++) {
        int r = r0 + j;
        if (r < N_NODES) {
            half4_t hh = {(_Float16)acc[j].x, (_Float16)acc[j].y,
                          (_Float16)acc[j].z, (_Float16)acc[j].w};
            *(half4_t*)(h16 + (size_t)r * D + q * 4) = hh;   // 8B, coalesced
        }
    }
}

// one wave per dst node. Weight phase: lane = edge (64-edge chunks).
// Gather phase: group g = lane>>4 picks the edge, q = lane&15 picks half4.
__global__ __launch_bounds__(256) void k_aggr(
    const int* __restrict__ off, const int* __restrict__ csr,
    const _Float16* __restrict__ h16, const float* __restrict__ a_s,
    const float* __restrict__ a_d, const float* __restrict__ bias,
    float* __restrict__ out, int do_relu) {
    int node = (blockIdx.x * blockDim.x + threadIdx.x) >> 6;
    int lane = threadIdx.x & 63;
    if (node >= N_NODES) return;
    int g = lane >> 4, q = lane & 15;
    int beg = off[node], end = off[node + 1];
    float ad = a_d[node];
    float s = 0.f;
    float4 acc = {0.f, 0.f, 0.f, 0.f};
    for (int c = beg; c < end; c += 64) {
        int idx = c + lane;
        int sv = 0;
        float w = 0.f;
        if (idx < end) {
            sv = csr[idx];
            float tv = a_s[sv] + ad;
            tv = fmaxf(tv, NEG_SLOPE * tv);  // leaky_relu, slope<1
            w = __expf(tv);                  // softmax shift dropped (|e| small)
        }
        float ws = w;
#pragma unroll
        for (int sft = 32; sft > 0; sft >>= 1) ws += __shfl_xor(ws, sft);
        s += ws;
        int cnt = min(end - c, 64);
        int iters = (cnt + 3) >> 2;
        for (int i = 0; i < iters; i++) {
            int j = i * 4 + g;               // w==0 for tail edges -> safe
            float wj = __shfl(w, j);
            int svj = __shfl(sv, j);
            half4_t hv = *(const half4_t*)(h16 + (size_t)svj * D + q * 4);
            acc.x = fmaf(wj, (float)hv.x, acc.x);
            acc.y = fmaf(wj, (float)hv.y, acc.y);
            acc.z = fmaf(wj, (float)hv.z, acc.z);
            acc.w = fmaf(wj, (float)hv.w, acc.w);
        }
    }
#pragma unroll
    for (int sft = 16; sft <= 32; sft <<= 1) {
        acc.x += __shfl_xor(acc.x, sft);
        acc.y += __shfl_xor(acc.y, sft);
        acc.z += __shfl_xor(acc.z, sft);
        acc.w += __shfl_xor(acc.w, sft);
    }
    if (g == 0) {
        float inv = 1.f / (s + SM_EPS);
        float4 b4 = ((const float4*)bias)[q];
        float4 o;
        o.x = fmaf(acc.x, inv, b4.x);
        o.y = fmaf(acc.y, inv, b4.y);
        o.z = fmaf(acc.z, inv, b4.z);
        o.w = fmaf(acc.w, inv, b4.w);
        if (do_relu) {
            o.x = fmaxf(o.x, 0.f); o.y = fmaxf(o.y, 0.f);
            o.z = fmaxf(o.z, 0.f); o.w = fmaxf(o.w, 0.f);
        }
        ((float4*)(out + (size_t)node * D))[q] = o;
    }
}

// ---------------- launch ----------------

extern "C" void kernel_launch(void* const* d_in, const int* in_sizes, int n_in,
                              void* d_out, int out_size, void* d_ws, size_t ws_size,
                              hipStream_t stream) {
    const float* x   = (const float*)d_in[0];
    const int*   ei  = (const int*)d_in[1];
    const float* W1  = (const float*)d_in[2];
    const float* as1 = (const float*)d_in[3];
    const float* ad1 = (const float*)d_in[4];
    const float* b1  = (const float*)d_in[5];
    const float* W2  = (const float*)d_in[6];
    const float* as2 = (const float*)d_in[7];
    const float* ad2 = (const float*)d_in[8];
    const float* b2  = (const float*)d_in[9];
    float* out = (float*)d_out;

    const int* src = ei;
    const int* dst = ei + N_EDGES;

    char* ws = (char*)d_ws;
    size_t o = 0;
    auto alloc = [&](size_t bytes) { void* p = ws + o; o += (bytes + 255) & ~255ull; return p; };
    _Float16* h16 = (_Float16*)alloc((size_t)N_NODES * D * sizeof(_Float16)); // 12.8 MB
    float* a_s   = (float*)alloc(N_NODES * sizeof(float));
    float* a_d   = (float*)alloc(N_NODES * sizeof(float));
    int*   off   = (int*)alloc((N_NODES + 1) * sizeof(int));
    int*   csr   = (int*)alloc(N_EDGES * sizeof(int));                  // 6.4 MB
    int*   gbh   = (int*)alloc(NB * PAD * sizeof(int));
    int*   bbase = (int*)alloc((NB + 1) * sizeof(int));
    int*   bcur  = (int*)alloc(NB * PAD * sizeof(int));
    float* wv    = (float*)alloc(4 * D * sizeof(float));
    // ebuf aliases h16: CSR build completes before k_gemm writes h16
    unsigned* ebuf = (unsigned*)h16;                                    // 6.4 MB < 12.8 MB

    // ---- precompute W@att vectors (both layers) ----
    k_wvec<<<1, 256, 0, stream>>>(W1, as1, ad1, W2, as2, ad2, wv);

    // ---- CSR by dst (two-level counting sort; shared by both layers) ----
    hipMemsetAsync(gbh, 0, NB * PAD * sizeof(int), stream);
    k_bhist   <<<NWG_E, TPB, 0, stream>>>(dst, gbh);
    k_scan_nb <<<1, 256, 0, stream>>>(gbh, bbase, bcur);
    k_bscatter<<<NWG_E, TPB, 0, stream>>>(src, dst, bcur, ebuf);
    k_bcsr    <<<NB, TPB, 0, stream>>>(bbase, ebuf, off, csr);

    // ---- layer 1: x -> out (relu'd) ----
    k_attn<<<(N_NODES + 255) / 256, 256, 0, stream>>>(x, wv, a_s, a_d);
    k_gemm<<<NWG_GEMM, 256, 0, stream>>>(x, W1, h16);
    k_aggr<<<N_NODES / 4, 256, 0, stream>>>(off, csr, h16, a_s, a_d, b1, out, 1);

    // ---- layer 2: out -> out ----
    k_attn<<<(N_NODES + 255) / 256, 256, 0, stream>>>(out, wv + 2 * D, a_s, a_d);
    k_gemm<<<NWG_GEMM, 256, 0, stream>>>(out, W2, h16);
    k_aggr<<<N_NODES / 4, 256, 0, stream>>>(off, csr, h16, a_s, a_d, b2, out, 0);
}

// Round 7
// 293.909 us; speedup vs baseline: 1.7378x; 1.0948x over previous
//
#include <hip/hip_runtime.h>

#define N_NODES 100000
#define N_EDGES 1600000
#define D 64
#define NEG_SLOPE 0.2f
#define SM_EPS 1e-16f

#define BSHIFT 9
#define BSIZE (1 << BSHIFT)                          // 512 dsts per bucket
#define NB ((N_NODES + BSIZE - 1) >> BSHIFT)         // 196 buckets
#define PAD 16                                        // 64B stride for global counters
#define TPB 256
#define EPT 16
#define TILE (TPB * EPT)                              // 4096 edges per block
#define NWG_E ((N_EDGES + TILE - 1) / TILE)           // 391
#define CSR_CAP 10240                                 // bucket mean 8192, sigma 90

#define GEMM_RR 8                                     // rows per thread
#define GEMM_ROWS 128                                 // rows per block (16 groups x 8)
#define NWG_GEMM ((N_NODES + GEMM_ROWS - 1) / GEMM_ROWS)  // 782

#define COMP(v, kk) ((kk) == 0 ? (v).x : (kk) == 1 ? (v).y : (kk) == 2 ? (v).z : (v).w)

typedef _Float16 half4_t __attribute__((ext_vector_type(4)));   // 8 B

// ---------------- CSR build: two-level counting sort by dst ----------------

__global__ __launch_bounds__(TPB) void k_bhist(const int* __restrict__ dst,
                                               int* __restrict__ gbh) {
    __shared__ int hist[NB];
    int t = threadIdx.x;
    for (int i = t; i < NB; i += TPB) hist[i] = 0;
    __syncthreads();
    int base = blockIdx.x * TILE;
#pragma unroll
    for (int j = 0; j < EPT; j++) {
        int i = base + j * TPB + t;
        if (i < N_EDGES) atomicAdd(&hist[dst[i] >> BSHIFT], 1);
    }
    __syncthreads();
    for (int i = t; i < NB; i += TPB)
        if (hist[i]) atomicAdd(&gbh[i * PAD], hist[i]);
}

__global__ __launch_bounds__(256) void k_scan_nb(const int* __restrict__ gbh,
                                                 int* __restrict__ bbase,
                                                 int* __restrict__ bcur) {
    __shared__ int lds[256];
    int t = threadIdx.x;
    int v = (t < NB) ? gbh[t * PAD] : 0;
    lds[t] = v;
    __syncthreads();
    for (int s = 1; s < 256; s <<= 1) {
        int a = (t >= s) ? lds[t - s] : 0;
        __syncthreads();
        lds[t] += a;
        __syncthreads();
    }
    int excl = lds[t] - v;
    if (t < NB) { bbase[t] = excl; bcur[t * PAD] = excl; }
    if (t == 0) bbase[NB] = N_EDGES;
}

// scatter edges into coarse bucket regions. LDS-staged in bucket-sorted order
// so global writes are contiguous runs per bucket (no 4B-line amplification).
__global__ __launch_bounds__(TPB) void k_bscatter(const int* __restrict__ src,
                                                  const int* __restrict__ dst,
                                                  int* __restrict__ bcur,
                                                  unsigned* __restrict__ ebuf) {
    __shared__ int hist[NB];
    __shared__ int cursor[NB];
    __shared__ int lbase[NB];       // global_base - local_excl per bucket
    __shared__ int tsum[TPB];
    __shared__ unsigned stage[TILE];      // 16 KB
    __shared__ int stageaddr[TILE];       // 16 KB
    int t = threadIdx.x;
    for (int i = t; i < NB; i += TPB) hist[i] = 0;
    __syncthreads();
    int base = blockIdx.x * TILE;
#pragma unroll
    for (int j = 0; j < EPT; j++) {
        int i = base + j * TPB + t;
        if (i < N_EDGES) atomicAdd(&hist[dst[i] >> BSHIFT], 1);
    }
    __syncthreads();
    // exclusive scan of the 196 bucket counts (block-local)
    int v = (t < NB) ? hist[t] : 0;
    tsum[t] = v;
    __syncthreads();
    for (int s = 1; s < 256; s <<= 1) {
        int a = (t >= s) ? tsum[t - s] : 0;
        __syncthreads();
        tsum[t] += a;
        __syncthreads();
    }
    int excl = tsum[t] - v;
    if (t < NB) {
        int gb = v ? atomicAdd(&bcur[t * PAD], v) : 0;
        lbase[t] = gb - excl;       // gaddr = lbase[b] + stage_slot
        cursor[t] = excl;
    }
    __syncthreads();
    // scatter into LDS stage (bucket-sorted order within block)
#pragma unroll
    for (int j = 0; j < EPT; j++) {
        int i = base + j * TPB + t;
        if (i < N_EDGES) {
            int d = dst[i];
            int b = d >> BSHIFT;
            int r = atomicAdd(&cursor[b], 1);           // LDS atomic
            stage[r] = (unsigned)src[i] | ((unsigned)(d & (BSIZE - 1)) << 17);
            stageaddr[r] = lbase[b] + r;
        }
    }
    __syncthreads();
    // write out: consecutive slots -> consecutive global addresses per bucket
    int total = min(TILE, N_EDGES - base);
    for (int s = t; s < total; s += TPB) ebuf[stageaddr[s]] = stage[s];
}

// per-bucket fine CSR: LDS hist over 512 dsts, scan, LDS-staged scatter,
// perfectly-coalesced final write.
__global__ __launch_bounds__(TPB) void k_bcsr(const int* __restrict__ bbase,
                                              const unsigned* __restrict__ ebuf,
                                              int* __restrict__ off,
                                              int* __restrict__ csr) {
    __shared__ int dh[BSIZE];   // hist, then cursor
    __shared__ int dl[BSIZE];   // bucket-local exclusive scan
    __shared__ int tsum[TPB];
    __shared__ int stage[CSR_CAP];   // 40 KB
    int b = blockIdx.x;
    int t = threadIdx.x;
    int beg = bbase[b], end = bbase[b + 1];
    int cnt = end - beg;
    dh[t] = 0; dh[t + TPB] = 0;
    __syncthreads();
    for (int i = beg + t; i < end; i += TPB)
        atomicAdd(&dh[(ebuf[i] >> 17) & (BSIZE - 1)], 1);
    __syncthreads();
    int v0 = dh[2 * t], v1 = dh[2 * t + 1];
    tsum[t] = v0 + v1;
    __syncthreads();
    for (int s = 1; s < 256; s <<= 1) {
        int a = (t >= s) ? tsum[t - s] : 0;
        __syncthreads();
        tsum[t] += a;
        __syncthreads();
    }
    int excl = tsum[t] - (v0 + v1);
    dl[2 * t] = excl;
    dl[2 * t + 1] = excl + v0;
    int gd = (b << BSHIFT) + 2 * t;
    if (gd < N_NODES) off[gd] = beg + excl;
    if (gd + 1 < N_NODES) off[gd + 1] = beg + excl + v0;
    if (b == 0 && t == 0) off[N_NODES] = N_EDGES;
    dh[2 * t] = 0; dh[2 * t + 1] = 0;       // reset cursors
    __syncthreads();
    if (cnt <= CSR_CAP) {
        // staged: scatter to LDS, then dense coalesced global write
        for (int i = beg + t; i < end; i += TPB) {
            unsigned pk = ebuf[i];
            int ld = (pk >> 17) & (BSIZE - 1);
            int r = atomicAdd(&dh[ld], 1);  // LDS atomic
            stage[dl[ld] + r] = (int)(pk & 0x1FFFFu);
        }
        __syncthreads();
        for (int s = t; s < cnt; s += TPB) csr[beg + s] = stage[s];
    } else {
        // fallback (statistically unreachable): direct scatter
        for (int i = beg + t; i < end; i += TPB) {
            unsigned pk = ebuf[i];
            int ld = (pk >> 17) & (BSIZE - 1);
            int r = atomicAdd(&dh[ld], 1);
            csr[beg + dl[ld] + r] = (int)(pk & 0x1FFFFu);
        }
    }
}

// ---------------- per-layer kernels ----------------

// h16 = fp16(x @ W); a_s = h.att_src, a_d = h.att_dst fused in the epilogue
// (computed from fp32 acc + 16-lane shfl reduce). W in LDS; thread
// (g=t>>4, q=t&15) owns an 8-row x 4-col register tile.
__global__ __launch_bounds__(256) void k_gemm(
    const float* __restrict__ x, const float* __restrict__ W,
    const float* __restrict__ att_s, const float* __restrict__ att_d,
    _Float16* __restrict__ h16, float* __restrict__ a_s,
    float* __restrict__ a_d) {
    __shared__ float4 Wl4[D * D / 4];                 // 16 KB
    int t = threadIdx.x;
    const float4* W4 = (const float4*)W;
#pragma unroll
    for (int i = 0; i < 4; i++) Wl4[i * 256 + t] = W4[i * 256 + t];
    __syncthreads();
    int q = t & 15;
    float4 as4 = ((const float4*)att_s)[q];
    float4 ad4 = ((const float4*)att_d)[q];
    int r0 = blockIdx.x * GEMM_ROWS + (t >> 4) * GEMM_RR;
    const float4* x4 = (const float4*)x;
    float4 acc[GEMM_RR];
#pragma unroll
    for (int j = 0; j < GEMM_RR; j++) acc[j] = {0.f, 0.f, 0.f, 0.f};
    for (int k4 = 0; k4 < D / 4; k4++) {
        float4 xv[GEMM_RR];
#pragma unroll
        for (int j = 0; j < GEMM_RR; j++) {
            int r = r0 + j;
            r = (r < N_NODES) ? r : N_NODES - 1;       // clamp (tail block)
            xv[j] = x4[(size_t)r * (D / 4) + k4];      // broadcast across 16 lanes
        }
#pragma unroll
        for (int kk = 0; kk < 4; kk++) {
            float4 w4 = Wl4[(k4 * 4 + kk) * 16 + q];
#pragma unroll
            for (int j = 0; j < GEMM_RR; j++) {
                float xs = COMP(xv[j], kk);
                acc[j].x = fmaf(xs, w4.x, acc[j].x);
                acc[j].y = fmaf(xs, w4.y, acc[j].y);
                acc[j].z = fmaf(xs, w4.z, acc[j].z);
                acc[j].w = fmaf(xs, w4.w, acc[j].w);
            }
        }
    }
#pragma unroll
    for (int j = 0; j < GEMM_RR; j++) {
        int r = r0 + j;
        if (r < N_NODES) {
            half4_t hh = {(_Float16)acc[j].x, (_Float16)acc[j].y,
                          (_Float16)acc[j].z, (_Float16)acc[j].w};
            *(half4_t*)(h16 + (size_t)r * D + q * 4) = hh;   // 8B, coalesced
        }
        // attn partial dots + 16-lane reduce (shfl_xor 1..8 stays in group)
        float sp = acc[j].x * as4.x + acc[j].y * as4.y +
                   acc[j].z * as4.z + acc[j].w * as4.w;
        float dp = acc[j].x * ad4.x + acc[j].y * ad4.y +
                   acc[j].z * ad4.z + acc[j].w * ad4.w;
#pragma unroll
        for (int s = 1; s <= 8; s <<= 1) {
            sp += __shfl_xor(sp, s);
            dp += __shfl_xor(dp, s);
        }
        if (q == 0 && r < N_NODES) { a_s[r] = sp; a_d[r] = dp; }
    }
}

// one 16-lane group per dst node (4 nodes/wave). Lane q holds features
// 4q..4q+3 (the acc IS the output: no cross-group reduce). Weight phase:
// lane = edge within 16-edge chunk; 4-step group shfl reduce for the denom.
__global__ __launch_bounds__(256) void k_aggr(
    const int* __restrict__ off, const int* __restrict__ csr,
    const _Float16* __restrict__ h16, const float* __restrict__ a_s,
    const float* __restrict__ a_d, const float* __restrict__ bias,
    float* __restrict__ out, int do_relu) {
    int node = (blockIdx.x * blockDim.x + threadIdx.x) >> 4;
    int q = threadIdx.x & 15;
    int gbase = threadIdx.x & 48;        // group base lane within wave
    if (node >= N_NODES) return;
    int beg = off[node], end = off[node + 1];
    float ad = a_d[node];
    float s = 0.f;
    float4 acc = {0.f, 0.f, 0.f, 0.f};
    for (int c = beg; c < end; c += 16) {
        int idx = c + q;
        int sv = 0;
        float w = 0.f;
        if (idx < end) {
            sv = csr[idx];
            float tv = a_s[sv] + ad;
            tv = fmaxf(tv, NEG_SLOPE * tv);  // leaky_relu, slope<1
            w = __expf(tv);                  // softmax shift dropped (|e| small)
        }
        float ws = w;
        ws += __shfl_xor(ws, 1); ws += __shfl_xor(ws, 2);
        ws += __shfl_xor(ws, 4); ws += __shfl_xor(ws, 8);
        s += ws;
        int cnt = min(end - c, 16);
        for (int j = 0; j < cnt; j++) {
            float wj = __shfl(w, gbase + j);
            int svj = __shfl(sv, gbase + j);
            half4_t hv = *(const half4_t*)(h16 + (size_t)svj * D + q * 4);
            acc.x = fmaf(wj, (float)hv.x, acc.x);
            acc.y = fmaf(wj, (float)hv.y, acc.y);
            acc.z = fmaf(wj, (float)hv.z, acc.z);
            acc.w = fmaf(wj, (float)hv.w, acc.w);
        }
    }
    float inv = 1.f / (s + SM_EPS);
    float4 b4 = ((const float4*)bias)[q];
    float4 o;
    o.x = fmaf(acc.x, inv, b4.x);
    o.y = fmaf(acc.y, inv, b4.y);
    o.z = fmaf(acc.z, inv, b4.z);
    o.w = fmaf(acc.w, inv, b4.w);
    if (do_relu) {
        o.x = fmaxf(o.x, 0.f); o.y = fmaxf(o.y, 0.f);
        o.z = fmaxf(o.z, 0.f); o.w = fmaxf(o.w, 0.f);
    }
    ((float4*)(out + (size_t)node * D))[q] = o;
}

// ---------------- launch ----------------

extern "C" void kernel_launch(void* const* d_in, const int* in_sizes, int n_in,
                              void* d_out, int out_size, void* d_ws, size_t ws_size,
                              hipStream_t stream) {
    const float* x   = (const float*)d_in[0];
    const int*   ei  = (const int*)d_in[1];
    const float* W1  = (const float*)d_in[2];
    const float* as1 = (const float*)d_in[3];
    const float* ad1 = (const float*)d_in[4];
    const float* b1  = (const float*)d_in[5];
    const float* W2  = (const float*)d_in[6];
    const float* as2 = (const float*)d_in[7];
    const float* ad2 = (const float*)d_in[8];
    const float* b2  = (const float*)d_in[9];
    float* out = (float*)d_out;

    const int* src = ei;
    const int* dst = ei + N_EDGES;

    char* ws = (char*)d_ws;
    size_t o = 0;
    auto alloc = [&](size_t bytes) { void* p = ws + o; o += (bytes + 255) & ~255ull; return p; };
    _Float16* h16 = (_Float16*)alloc((size_t)N_NODES * D * sizeof(_Float16)); // 12.8 MB
    float* a_s   = (float*)alloc(N_NODES * sizeof(float));
    float* a_d   = (float*)alloc(N_NODES * sizeof(float));
    int*   off   = (int*)alloc((N_NODES + 1) * sizeof(int));
    int*   csr   = (int*)alloc(N_EDGES * sizeof(int));                  // 6.4 MB
    int*   gbh   = (int*)alloc(NB * PAD * sizeof(int));
    int*   bbase = (int*)alloc((NB + 1) * sizeof(int));
    int*   bcur  = (int*)alloc(NB * PAD * sizeof(int));
    // ebuf aliases h16: CSR build completes before k_gemm writes h16
    unsigned* ebuf = (unsigned*)h16;                                    // 6.4 MB < 12.8 MB

    // ---- CSR by dst (two-level counting sort; shared by both layers) ----
    hipMemsetAsync(gbh, 0, NB * PAD * sizeof(int), stream);
    k_bhist   <<<NWG_E, TPB, 0, stream>>>(dst, gbh);
    k_scan_nb <<<1, 256, 0, stream>>>(gbh, bbase, bcur);
    k_bscatter<<<NWG_E, TPB, 0, stream>>>(src, dst, bcur, ebuf);
    k_bcsr    <<<NB, TPB, 0, stream>>>(bbase, ebuf, off, csr);

    // ---- layer 1: x -> out (relu'd) ----
    k_gemm<<<NWG_GEMM, 256, 0, stream>>>(x, W1, as1, ad1, h16, a_s, a_d);
    k_aggr<<<(N_NODES * 16 + 255) / 256, 256, 0, stream>>>(off, csr, h16, a_s, a_d, b1, out, 1);

    // ---- layer 2: out -> out ----
    k_gemm<<<NWG_GEMM, 256, 0, stream>>>(out, W2, as2, ad2, h16, a_s, a_d);
    k_aggr<<<(N_NODES * 16 + 255) / 256, 256, 0, stream>>>(off, csr, h16, a_s, a_d, b2, out, 0);
}

// Round 8
// 285.180 us; speedup vs baseline: 1.7910x; 1.0306x over previous
//
#include <hip/hip_runtime.h>

#define N_NODES 100000
#define N_EDGES 1600000
#define D 64
#define NEG_SLOPE 0.2f
#define SM_EPS 1e-16f

#define BSHIFT 9
#define BSIZE (1 << BSHIFT)                          // 512 dsts per bucket
#define NB ((N_NODES + BSIZE - 1) >> BSHIFT)         // 196 buckets
#define PAD 16                                        // 64B stride for global counters
#define TPB 256
#define EPT 16
#define TILE (TPB * EPT)                              // 4096 edges per block
#define NWG_E ((N_EDGES + TILE - 1) / TILE)           // 391
#define CSR_CAP 10240                                 // bucket mean 8192, sigma 90

#define GEMM_RR 8                                     // rows per thread
#define GEMM_ROWS 128                                 // rows per block (16 groups x 8)
#define NWG_GEMM ((N_NODES + GEMM_ROWS - 1) / GEMM_ROWS)  // 782

#define COMP(v, kk) ((kk) == 0 ? (v).x : (kk) == 1 ? (v).y : (kk) == 2 ? (v).z : (v).w)

typedef _Float16 half4_t __attribute__((ext_vector_type(4)));   // 8 B

// ---------------- CSR build: two-level counting sort by dst ----------------

__global__ __launch_bounds__(TPB) void k_bhist(const int* __restrict__ dst,
                                               int* __restrict__ gbh) {
    __shared__ int hist[NB];
    int t = threadIdx.x;
    for (int i = t; i < NB; i += TPB) hist[i] = 0;
    __syncthreads();
    int base = blockIdx.x * TILE;
#pragma unroll
    for (int j = 0; j < EPT; j++) {
        int i = base + j * TPB + t;
        if (i < N_EDGES) atomicAdd(&hist[dst[i] >> BSHIFT], 1);
    }
    __syncthreads();
    for (int i = t; i < NB; i += TPB)
        if (hist[i]) atomicAdd(&gbh[i * PAD], hist[i]);
}

__global__ __launch_bounds__(256) void k_scan_nb(const int* __restrict__ gbh,
                                                 int* __restrict__ bbase,
                                                 int* __restrict__ bcur) {
    __shared__ int lds[256];
    int t = threadIdx.x;
    int v = (t < NB) ? gbh[t * PAD] : 0;
    lds[t] = v;
    __syncthreads();
    for (int s = 1; s < 256; s <<= 1) {
        int a = (t >= s) ? lds[t - s] : 0;
        __syncthreads();
        lds[t] += a;
        __syncthreads();
    }
    int excl = lds[t] - v;
    if (t < NB) { bbase[t] = excl; bcur[t * PAD] = excl; }
    if (t == 0) bbase[NB] = N_EDGES;
}

// scatter edges into coarse bucket regions. LDS-staged in bucket-sorted order
// so global writes are contiguous runs per bucket (no 4B-line amplification).
__global__ __launch_bounds__(TPB) void k_bscatter(const int* __restrict__ src,
                                                  const int* __restrict__ dst,
                                                  int* __restrict__ bcur,
                                                  unsigned* __restrict__ ebuf) {
    __shared__ int hist[NB];
    __shared__ int cursor[NB];
    __shared__ int lbase[NB];       // global_base - local_excl per bucket
    __shared__ int tsum[TPB];
    __shared__ unsigned stage[TILE];      // 16 KB
    __shared__ int stageaddr[TILE];       // 16 KB
    int t = threadIdx.x;
    for (int i = t; i < NB; i += TPB) hist[i] = 0;
    __syncthreads();
    int base = blockIdx.x * TILE;
#pragma unroll
    for (int j = 0; j < EPT; j++) {
        int i = base + j * TPB + t;
        if (i < N_EDGES) atomicAdd(&hist[dst[i] >> BSHIFT], 1);
    }
    __syncthreads();
    // exclusive scan of the 196 bucket counts (block-local)
    int v = (t < NB) ? hist[t] : 0;
    tsum[t] = v;
    __syncthreads();
    for (int s = 1; s < 256; s <<= 1) {
        int a = (t >= s) ? tsum[t - s] : 0;
        __syncthreads();
        tsum[t] += a;
        __syncthreads();
    }
    int excl = tsum[t] - v;
    if (t < NB) {
        int gb = v ? atomicAdd(&bcur[t * PAD], v) : 0;
        lbase[t] = gb - excl;       // gaddr = lbase[b] + stage_slot
        cursor[t] = excl;
    }
    __syncthreads();
    // scatter into LDS stage (bucket-sorted order within block)
#pragma unroll
    for (int j = 0; j < EPT; j++) {
        int i = base + j * TPB + t;
        if (i < N_EDGES) {
            int d = dst[i];
            int b = d >> BSHIFT;
            int r = atomicAdd(&cursor[b], 1);           // LDS atomic
            stage[r] = (unsigned)src[i] | ((unsigned)(d & (BSIZE - 1)) << 17);
            stageaddr[r] = lbase[b] + r;
        }
    }
    __syncthreads();
    // write out: consecutive slots -> consecutive global addresses per bucket
    int total = min(TILE, N_EDGES - base);
    for (int s = t; s < total; s += TPB) ebuf[stageaddr[s]] = stage[s];
}

// per-bucket fine CSR: LDS hist over 512 dsts, scan, LDS-staged scatter,
// perfectly-coalesced final write.
__global__ __launch_bounds__(TPB) void k_bcsr(const int* __restrict__ bbase,
                                              const unsigned* __restrict__ ebuf,
                                              int* __restrict__ off,
                                              int* __restrict__ csr) {
    __shared__ int dh[BSIZE];   // hist, then cursor
    __shared__ int dl[BSIZE];   // bucket-local exclusive scan
    __shared__ int tsum[TPB];
    __shared__ int stage[CSR_CAP];   // 40 KB
    int b = blockIdx.x;
    int t = threadIdx.x;
    int beg = bbase[b], end = bbase[b + 1];
    int cnt = end - beg;
    dh[t] = 0; dh[t + TPB] = 0;
    __syncthreads();
    for (int i = beg + t; i < end; i += TPB)
        atomicAdd(&dh[(ebuf[i] >> 17) & (BSIZE - 1)], 1);
    __syncthreads();
    int v0 = dh[2 * t], v1 = dh[2 * t + 1];
    tsum[t] = v0 + v1;
    __syncthreads();
    for (int s = 1; s < 256; s <<= 1) {
        int a = (t >= s) ? tsum[t - s] : 0;
        __syncthreads();
        tsum[t] += a;
        __syncthreads();
    }
    int excl = tsum[t] - (v0 + v1);
    dl[2 * t] = excl;
    dl[2 * t + 1] = excl + v0;
    int gd = (b << BSHIFT) + 2 * t;
    if (gd < N_NODES) off[gd] = beg + excl;
    if (gd + 1 < N_NODES) off[gd + 1] = beg + excl + v0;
    if (b == 0 && t == 0) off[N_NODES] = N_EDGES;
    dh[2 * t] = 0; dh[2 * t + 1] = 0;       // reset cursors
    __syncthreads();
    if (cnt <= CSR_CAP) {
        // staged: scatter to LDS, then dense coalesced global write
        for (int i = beg + t; i < end; i += TPB) {
            unsigned pk = ebuf[i];
            int ld = (pk >> 17) & (BSIZE - 1);
            int r = atomicAdd(&dh[ld], 1);  // LDS atomic
            stage[dl[ld] + r] = (int)(pk & 0x1FFFFu);
        }
        __syncthreads();
        for (int s = t; s < cnt; s += TPB) csr[beg + s] = stage[s];
    } else {
        // fallback (statistically unreachable): direct scatter
        for (int i = beg + t; i < end; i += TPB) {
            unsigned pk = ebuf[i];
            int ld = (pk >> 17) & (BSIZE - 1);
            int r = atomicAdd(&dh[ld], 1);
            csr[beg + dl[ld] + r] = (int)(pk & 0x1FFFFu);
        }
    }
}

// ---------------- per-layer kernels ----------------

// Precompute wv = [W1@att_src1, W1@att_dst1, W2@att_src2, W2@att_dst2] (4x64).
__global__ __launch_bounds__(256) void k_wvec(
    const float* __restrict__ W1, const float* __restrict__ as1,
    const float* __restrict__ ad1, const float* __restrict__ W2,
    const float* __restrict__ as2, const float* __restrict__ ad2,
    float* __restrict__ wv) {
    int w = threadIdx.x >> 6, lane = threadIdx.x & 63;
    const float* W  = (w < 2) ? W1 : W2;
    const float* av = (w == 0) ? as1 : (w == 1) ? ad1 : (w == 2) ? as2 : ad2;
    const float4* Wr = (const float4*)(W + lane * D);
    const float4* a4 = (const float4*)av;
    float acc0 = 0.f, acc1 = 0.f;
#pragma unroll
    for (int c = 0; c < D / 8; c++) {
        float4 w0 = Wr[2 * c], w1 = Wr[2 * c + 1];
        float4 v0 = a4[2 * c], v1 = a4[2 * c + 1];
        acc0 += w0.x * v0.x + w0.y * v0.y + w0.z * v0.z + w0.w * v0.w;
        acc1 += w1.x * v1.x + w1.y * v1.y + w1.z * v1.z + w1.w * v1.w;
    }
    wv[w * D + lane] = acc0 + acc1;
}

// a_s = x . wsv ; a_d = x . wdv — one thread per row (a_s = h.att == x.(W@att)).
__global__ __launch_bounds__(256) void k_attn(
    const float* __restrict__ x, const float* __restrict__ wv,
    float* __restrict__ a_s, float* __restrict__ a_d) {
    __shared__ float4 wvs[D / 4], wvd[D / 4];
    int t = threadIdx.x;
    if (t < D / 4) wvs[t] = ((const float4*)wv)[t];
    else if (t < D / 2) wvd[t - D / 4] = ((const float4*)(wv + D))[t - D / 4];
    __syncthreads();
    int r = blockIdx.x * 256 + t;
    if (r >= N_NODES) return;
    const float4* x4 = (const float4*)(x + (size_t)r * D);
    float s = 0.f, e = 0.f;
#pragma unroll
    for (int k4 = 0; k4 < D / 4; k4++) {
        float4 xv = x4[k4];
        float4 a = wvs[k4], b = wvd[k4];
        s += xv.x * a.x + xv.y * a.y + xv.z * a.z + xv.w * a.w;
        e += xv.x * b.x + xv.y * b.y + xv.z * b.z + xv.w * b.w;
    }
    a_s[r] = s;
    a_d[r] = e;
}

// h16 = fp16(x @ W). W in LDS; thread (g=t>>4, q=t&15) computes an 8-row x
// 4-col register tile. Pure GEMM — no cross-lane ops.
__global__ __launch_bounds__(256) void k_gemm(
    const float* __restrict__ x, const float* __restrict__ W,
    _Float16* __restrict__ h16) {
    __shared__ float4 Wl4[D * D / 4];                 // 16 KB
    int t = threadIdx.x;
    const float4* W4 = (const float4*)W;
#pragma unroll
    for (int i = 0; i < 4; i++) Wl4[i * 256 + t] = W4[i * 256 + t];
    __syncthreads();
    int q = t & 15;
    int r0 = blockIdx.x * GEMM_ROWS + (t >> 4) * GEMM_RR;
    const float4* x4 = (const float4*)x;
    float4 acc[GEMM_RR];
#pragma unroll
    for (int j = 0; j < GEMM_RR; j++) acc[j] = {0.f, 0.f, 0.f, 0.f};
    for (int k4 = 0; k4 < D / 4; k4++) {
        float4 xv[GEMM_RR];
#pragma unroll
        for (int j = 0; j < GEMM_RR; j++) {
            int r = r0 + j;
            r = (r < N_NODES) ? r : N_NODES - 1;       // clamp (tail block)
            xv[j] = x4[(size_t)r * (D / 4) + k4];      // broadcast across 16 lanes
        }
#pragma unroll
        for (int kk = 0; kk < 4; kk++) {
            float4 w4 = Wl4[(k4 * 4 + kk) * 16 + q];
#pragma unroll
            for (int j = 0; j < GEMM_RR; j++) {
                float xs = COMP(xv[j], kk);
                acc[j].x = fmaf(xs, w4.x, acc[j].x);
                acc[j].y = fmaf(xs, w4.y, acc[j].y);
                acc[j].z = fmaf(xs, w4.z, acc[j].z);
                acc[j].w = fmaf(xs, w4.w, acc[j].w);
            }
        }
    }
#pragma unroll
    for (int j = 0; j < GEMM_RR; j++) {
        int r = r0 + j;
        if (r < N_NODES) {
            half4_t hh = {(_Float16)acc[j].x, (_Float16)acc[j].y,
                          (_Float16)acc[j].z, (_Float16)acc[j].w};
            *(half4_t*)(h16 + (size_t)r * D + q * 4) = hh;   // 8B, coalesced
        }
    }
}

// one 16-lane group per dst node (4 nodes/wave), lane q = features 4q..4q+3.
// ZERO cross-lane ops: every lane redundantly computes each edge's weight
// (csr/a_s reads are same-address broadcast loads, L1/L2-hot), so the
// softmax denom is lane-local and the gather chain has no LDS-pipe serialization.
// 4x unrolled body -> 4 independent gather chains in flight.
__global__ __launch_bounds__(256) void k_aggr(
    const int* __restrict__ off, const int* __restrict__ csr,
    const _Float16* __restrict__ h16, const float* __restrict__ a_s,
    const float* __restrict__ a_d, const float* __restrict__ bias,
    float* __restrict__ out, int do_relu) {
    int node = (blockIdx.x * blockDim.x + threadIdx.x) >> 4;
    int q = threadIdx.x & 15;
    if (node >= N_NODES) return;
    int beg = off[node], end = off[node + 1];
    float ad = a_d[node];
    float s = 0.f;
    float4 acc = {0.f, 0.f, 0.f, 0.f};
    int c = beg;
    for (; c + 4 <= end; c += 4) {
        int v0 = csr[c], v1 = csr[c + 1], v2 = csr[c + 2], v3 = csr[c + 3];
        float t0 = a_s[v0] + ad, t1 = a_s[v1] + ad;
        float t2 = a_s[v2] + ad, t3 = a_s[v3] + ad;
        t0 = fmaxf(t0, NEG_SLOPE * t0); t1 = fmaxf(t1, NEG_SLOPE * t1);
        t2 = fmaxf(t2, NEG_SLOPE * t2); t3 = fmaxf(t3, NEG_SLOPE * t3);
        float w0 = __expf(t0), w1 = __expf(t1);
        float w2 = __expf(t2), w3 = __expf(t3);
        half4_t h0 = *(const half4_t*)(h16 + (size_t)v0 * D + q * 4);
        half4_t h1 = *(const half4_t*)(h16 + (size_t)v1 * D + q * 4);
        half4_t h2 = *(const half4_t*)(h16 + (size_t)v2 * D + q * 4);
        half4_t h3 = *(const half4_t*)(h16 + (size_t)v3 * D + q * 4);
        s += (w0 + w1) + (w2 + w3);
        acc.x = fmaf(w0, (float)h0.x, acc.x); acc.y = fmaf(w0, (float)h0.y, acc.y);
        acc.z = fmaf(w0, (float)h0.z, acc.z); acc.w = fmaf(w0, (float)h0.w, acc.w);
        acc.x = fmaf(w1, (float)h1.x, acc.x); acc.y = fmaf(w1, (float)h1.y, acc.y);
        acc.z = fmaf(w1, (float)h1.z, acc.z); acc.w = fmaf(w1, (float)h1.w, acc.w);
        acc.x = fmaf(w2, (float)h2.x, acc.x); acc.y = fmaf(w2, (float)h2.y, acc.y);
        acc.z = fmaf(w2, (float)h2.z, acc.z); acc.w = fmaf(w2, (float)h2.w, acc.w);
        acc.x = fmaf(w3, (float)h3.x, acc.x); acc.y = fmaf(w3, (float)h3.y, acc.y);
        acc.z = fmaf(w3, (float)h3.z, acc.z); acc.w = fmaf(w3, (float)h3.w, acc.w);
    }
    for (; c < end; c++) {
        int v = csr[c];
        float tv = a_s[v] + ad;
        tv = fmaxf(tv, NEG_SLOPE * tv);
        float w = __expf(tv);
        half4_t hv = *(const half4_t*)(h16 + (size_t)v * D + q * 4);
        s += w;
        acc.x = fmaf(w, (float)hv.x, acc.x); acc.y = fmaf(w, (float)hv.y, acc.y);
        acc.z = fmaf(w, (float)hv.z, acc.z); acc.w = fmaf(w, (float)hv.w, acc.w);
    }
    float inv = 1.f / (s + SM_EPS);
    float4 b4 = ((const float4*)bias)[q];
    float4 o;
    o.x = fmaf(acc.x, inv, b4.x);
    o.y = fmaf(acc.y, inv, b4.y);
    o.z = fmaf(acc.z, inv, b4.z);
    o.w = fmaf(acc.w, inv, b4.w);
    if (do_relu) {
        o.x = fmaxf(o.x, 0.f); o.y = fmaxf(o.y, 0.f);
        o.z = fmaxf(o.z, 0.f); o.w = fmaxf(o.w, 0.f);
    }
    ((float4*)(out + (size_t)node * D))[q] = o;
}

// ---------------- launch ----------------

extern "C" void kernel_launch(void* const* d_in, const int* in_sizes, int n_in,
                              void* d_out, int out_size, void* d_ws, size_t ws_size,
                              hipStream_t stream) {
    const float* x   = (const float*)d_in[0];
    const int*   ei  = (const int*)d_in[1];
    const float* W1  = (const float*)d_in[2];
    const float* as1 = (const float*)d_in[3];
    const float* ad1 = (const float*)d_in[4];
    const float* b1  = (const float*)d_in[5];
    const float* W2  = (const float*)d_in[6];
    const float* as2 = (const float*)d_in[7];
    const float* ad2 = (const float*)d_in[8];
    const float* b2  = (const float*)d_in[9];
    float* out = (float*)d_out;

    const int* src = ei;
    const int* dst = ei + N_EDGES;

    char* ws = (char*)d_ws;
    size_t o = 0;
    auto alloc = [&](size_t bytes) { void* p = ws + o; o += (bytes + 255) & ~255ull; return p; };
    _Float16* h16 = (_Float16*)alloc((size_t)N_NODES * D * sizeof(_Float16)); // 12.8 MB
    float* a_s   = (float*)alloc(N_NODES * sizeof(float));
    float* a_d   = (float*)alloc(N_NODES * sizeof(float));
    int*   off   = (int*)alloc((N_NODES + 1) * sizeof(int));
    int*   csr   = (int*)alloc(N_EDGES * sizeof(int));                  // 6.4 MB
    int*   gbh   = (int*)alloc(NB * PAD * sizeof(int));
    int*   bbase = (int*)alloc((NB + 1) * sizeof(int));
    int*   bcur  = (int*)alloc(NB * PAD * sizeof(int));
    float* wv    = (float*)alloc(4 * D * sizeof(float));
    // ebuf aliases h16: CSR build completes before k_gemm writes h16
    unsigned* ebuf = (unsigned*)h16;                                    // 6.4 MB < 12.8 MB

    // ---- precompute W@att vectors (both layers) ----
    k_wvec<<<1, 256, 0, stream>>>(W1, as1, ad1, W2, as2, ad2, wv);

    // ---- CSR by dst (two-level counting sort; shared by both layers) ----
    hipMemsetAsync(gbh, 0, NB * PAD * sizeof(int), stream);
    k_bhist   <<<NWG_E, TPB, 0, stream>>>(dst, gbh);
    k_scan_nb <<<1, 256, 0, stream>>>(gbh, bbase, bcur);
    k_bscatter<<<NWG_E, TPB, 0, stream>>>(src, dst, bcur, ebuf);
    k_bcsr    <<<NB, TPB, 0, stream>>>(bbase, ebuf, off, csr);

    // ---- layer 1: x -> out (relu'd) ----
    k_attn<<<(N_NODES + 255) / 256, 256, 0, stream>>>(x, wv, a_s, a_d);
    k_gemm<<<NWG_GEMM, 256, 0, stream>>>(x, W1, h16);
    k_aggr<<<(N_NODES * 16 + 255) / 256, 256, 0, stream>>>(off, csr, h16, a_s, a_d, b1, out, 1);

    // ---- layer 2: out -> out ----
    k_attn<<<(N_NODES + 255) / 256, 256, 0, stream>>>(out, wv + 2 * D, a_s, a_d);
    k_gemm<<<NWG_GEMM, 256, 0, stream>>>(out, W2, h16);
    k_aggr<<<(N_NODES * 16 + 255) / 256, 256, 0, stream>>>(off, csr, h16, a_s, a_d, b2, out, 0);
}

// Round 9
// 278.392 us; speedup vs baseline: 1.8346x; 1.0244x over previous
//
#include <hip/hip_runtime.h>

#define N_NODES 100000
#define N_EDGES 1600000
#define D 64
#define NEG_SLOPE 0.2f
#define SM_EPS 1e-16f

#define BSHIFT 9
#define BSIZE (1 << BSHIFT)                          // 512 dsts per bucket
#define NB ((N_NODES + BSIZE - 1) >> BSHIFT)         // 196 buckets
#define PAD 16                                        // 64B stride for global counters
#define TPB 256
#define EPT 16
#define TILE (TPB * EPT)                              // 4096 edges per block
#define NWG_E ((N_EDGES + TILE - 1) / TILE)           // 391
#define CSR_CAP 10240                                 // bucket mean 8192, sigma 90

#define GEMM_RR 8                                     // rows per thread
#define GEMM_ROWS 128                                 // rows per block (16 groups x 8)
#define NWG_GEMM ((N_NODES + GEMM_ROWS - 1) / GEMM_ROWS)  // 782

#define COMP(v, kk) ((kk) == 0 ? (v).x : (kk) == 1 ? (v).y : (kk) == 2 ? (v).z : (v).w)

typedef _Float16 half4_t __attribute__((ext_vector_type(4)));   // 8 B

// ---------------- CSR build: two-level counting sort by dst ----------------

__global__ __launch_bounds__(TPB) void k_bhist(const int* __restrict__ dst,
                                               int* __restrict__ gbh) {
    __shared__ int hist[NB];
    int t = threadIdx.x;
    for (int i = t; i < NB; i += TPB) hist[i] = 0;
    __syncthreads();
    int base = blockIdx.x * TILE;
#pragma unroll
    for (int j = 0; j < EPT; j++) {
        int i = base + j * TPB + t;
        if (i < N_EDGES) atomicAdd(&hist[dst[i] >> BSHIFT], 1);
    }
    __syncthreads();
    for (int i = t; i < NB; i += TPB)
        if (hist[i]) atomicAdd(&gbh[i * PAD], hist[i]);
}

__global__ __launch_bounds__(256) void k_scan_nb(const int* __restrict__ gbh,
                                                 int* __restrict__ bbase,
                                                 int* __restrict__ bcur) {
    __shared__ int lds[256];
    int t = threadIdx.x;
    int v = (t < NB) ? gbh[t * PAD] : 0;
    lds[t] = v;
    __syncthreads();
    for (int s = 1; s < 256; s <<= 1) {
        int a = (t >= s) ? lds[t - s] : 0;
        __syncthreads();
        lds[t] += a;
        __syncthreads();
    }
    int excl = lds[t] - v;
    if (t < NB) { bbase[t] = excl; bcur[t * PAD] = excl; }
    if (t == 0) bbase[NB] = N_EDGES;
}

// scatter edges into coarse bucket regions. LDS-staged in bucket-sorted order
// so global writes are contiguous runs per bucket (no 4B-line amplification).
__global__ __launch_bounds__(TPB) void k_bscatter(const int* __restrict__ src,
                                                  const int* __restrict__ dst,
                                                  int* __restrict__ bcur,
                                                  unsigned* __restrict__ ebuf) {
    __shared__ int hist[NB];
    __shared__ int cursor[NB];
    __shared__ int lbase[NB];       // global_base - local_excl per bucket
    __shared__ int tsum[TPB];
    __shared__ unsigned stage[TILE];      // 16 KB
    __shared__ int stageaddr[TILE];       // 16 KB
    int t = threadIdx.x;
    for (int i = t; i < NB; i += TPB) hist[i] = 0;
    __syncthreads();
    int base = blockIdx.x * TILE;
#pragma unroll
    for (int j = 0; j < EPT; j++) {
        int i = base + j * TPB + t;
        if (i < N_EDGES) atomicAdd(&hist[dst[i] >> BSHIFT], 1);
    }
    __syncthreads();
    // exclusive scan of the 196 bucket counts (block-local)
    int v = (t < NB) ? hist[t] : 0;
    tsum[t] = v;
    __syncthreads();
    for (int s = 1; s < 256; s <<= 1) {
        int a = (t >= s) ? tsum[t - s] : 0;
        __syncthreads();
        tsum[t] += a;
        __syncthreads();
    }
    int excl = tsum[t] - v;
    if (t < NB) {
        int gb = v ? atomicAdd(&bcur[t * PAD], v) : 0;
        lbase[t] = gb - excl;       // gaddr = lbase[b] + stage_slot
        cursor[t] = excl;
    }
    __syncthreads();
    // scatter into LDS stage (bucket-sorted order within block)
#pragma unroll
    for (int j = 0; j < EPT; j++) {
        int i = base + j * TPB + t;
        if (i < N_EDGES) {
            int d = dst[i];
            int b = d >> BSHIFT;
            int r = atomicAdd(&cursor[b], 1);           // LDS atomic
            stage[r] = (unsigned)src[i] | ((unsigned)(d & (BSIZE - 1)) << 17);
            stageaddr[r] = lbase[b] + r;
        }
    }
    __syncthreads();
    // write out: consecutive slots -> consecutive global addresses per bucket
    int total = min(TILE, N_EDGES - base);
    for (int s = t; s < total; s += TPB) ebuf[stageaddr[s]] = stage[s];
}

// per-bucket fine CSR: LDS hist over 512 dsts, scan, LDS-staged scatter,
// perfectly-coalesced final write.
__global__ __launch_bounds__(TPB) void k_bcsr(const int* __restrict__ bbase,
                                              const unsigned* __restrict__ ebuf,
                                              int* __restrict__ off,
                                              int* __restrict__ csr) {
    __shared__ int dh[BSIZE];   // hist, then cursor
    __shared__ int dl[BSIZE];   // bucket-local exclusive scan
    __shared__ int tsum[TPB];
    __shared__ int stage[CSR_CAP];   // 40 KB
    int b = blockIdx.x;
    int t = threadIdx.x;
    int beg = bbase[b], end = bbase[b + 1];
    int cnt = end - beg;
    dh[t] = 0; dh[t + TPB] = 0;
    __syncthreads();
    for (int i = beg + t; i < end; i += TPB)
        atomicAdd(&dh[(ebuf[i] >> 17) & (BSIZE - 1)], 1);
    __syncthreads();
    int v0 = dh[2 * t], v1 = dh[2 * t + 1];
    tsum[t] = v0 + v1;
    __syncthreads();
    for (int s = 1; s < 256; s <<= 1) {
        int a = (t >= s) ? tsum[t - s] : 0;
        __syncthreads();
        tsum[t] += a;
        __syncthreads();
    }
    int excl = tsum[t] - (v0 + v1);
    dl[2 * t] = excl;
    dl[2 * t + 1] = excl + v0;
    int gd = (b << BSHIFT) + 2 * t;
    if (gd < N_NODES) off[gd] = beg + excl;
    if (gd + 1 < N_NODES) off[gd + 1] = beg + excl + v0;
    if (b == 0 && t == 0) off[N_NODES] = N_EDGES;
    dh[2 * t] = 0; dh[2 * t + 1] = 0;       // reset cursors
    __syncthreads();
    if (cnt <= CSR_CAP) {
        // staged: scatter to LDS, then dense coalesced global write
        for (int i = beg + t; i < end; i += TPB) {
            unsigned pk = ebuf[i];
            int ld = (pk >> 17) & (BSIZE - 1);
            int r = atomicAdd(&dh[ld], 1);  // LDS atomic
            stage[dl[ld] + r] = (int)(pk & 0x1FFFFu);
        }
        __syncthreads();
        for (int s = t; s < cnt; s += TPB) csr[beg + s] = stage[s];
    } else {
        // fallback (statistically unreachable): direct scatter
        for (int i = beg + t; i < end; i += TPB) {
            unsigned pk = ebuf[i];
            int ld = (pk >> 17) & (BSIZE - 1);
            int r = atomicAdd(&dh[ld], 1);
            csr[beg + dl[ld] + r] = (int)(pk & 0x1FFFFu);
        }
    }
}

// ---------------- per-layer kernels ----------------

// Precompute wv = [W1@att_src1, W1@att_dst1, W2@att_src2, W2@att_dst2] (4x64).
__global__ __launch_bounds__(256) void k_wvec(
    const float* __restrict__ W1, const float* __restrict__ as1,
    const float* __restrict__ ad1, const float* __restrict__ W2,
    const float* __restrict__ as2, const float* __restrict__ ad2,
    float* __restrict__ wv) {
    int w = threadIdx.x >> 6, lane = threadIdx.x & 63;
    const float* W  = (w < 2) ? W1 : W2;
    const float* av = (w == 0) ? as1 : (w == 1) ? ad1 : (w == 2) ? as2 : ad2;
    const float4* Wr = (const float4*)(W + lane * D);
    const float4* a4 = (const float4*)av;
    float acc0 = 0.f, acc1 = 0.f;
#pragma unroll
    for (int c = 0; c < D / 8; c++) {
        float4 w0 = Wr[2 * c], w1 = Wr[2 * c + 1];
        float4 v0 = a4[2 * c], v1 = a4[2 * c + 1];
        acc0 += w0.x * v0.x + w0.y * v0.y + w0.z * v0.z + w0.w * v0.w;
        acc1 += w1.x * v1.x + w1.y * v1.y + w1.z * v1.z + w1.w * v1.w;
    }
    wv[w * D + lane] = acc0 + acc1;
}

// h16 = fp16(x @ W); a_s = x.wsv, a_d = x.wdv fused LANE-REDUNDANTLY
// (each thread reads its 8 rows fully via broadcast float4s, so the row dots
// accumulate with zero cross-lane ops; lane q==0 stores). W in LDS.
__global__ __launch_bounds__(256) void k_gemm(
    const float* __restrict__ x, const float* __restrict__ W,
    const float* __restrict__ wv,   // [wsv | wdv]
    _Float16* __restrict__ h16, float* __restrict__ a_s,
    float* __restrict__ a_d) {
    __shared__ float4 Wl4[D * D / 4];                 // 16 KB
    __shared__ float4 wvs[D / 4], wvd[D / 4];         // 512 B
    int t = threadIdx.x;
    const float4* W4 = (const float4*)W;
#pragma unroll
    for (int i = 0; i < 4; i++) Wl4[i * 256 + t] = W4[i * 256 + t];
    if (t < D / 4) wvs[t] = ((const float4*)wv)[t];
    else if (t < D / 2) wvd[t - D / 4] = ((const float4*)(wv + D))[t - D / 4];
    __syncthreads();
    int q = t & 15;
    int r0 = blockIdx.x * GEMM_ROWS + (t >> 4) * GEMM_RR;
    const float4* x4 = (const float4*)x;
    float4 acc[GEMM_RR];
    float sa[GEMM_RR], ea[GEMM_RR];
#pragma unroll
    for (int j = 0; j < GEMM_RR; j++) {
        acc[j] = {0.f, 0.f, 0.f, 0.f};
        sa[j] = 0.f; ea[j] = 0.f;
    }
    for (int k4 = 0; k4 < D / 4; k4++) {
        float4 ws4 = wvs[k4], wd4 = wvd[k4];
        float4 xv[GEMM_RR];
#pragma unroll
        for (int j = 0; j < GEMM_RR; j++) {
            int r = r0 + j;
            r = (r < N_NODES) ? r : N_NODES - 1;       // clamp (tail block)
            xv[j] = x4[(size_t)r * (D / 4) + k4];      // broadcast across 16 lanes
        }
#pragma unroll
        for (int j = 0; j < GEMM_RR; j++) {
            sa[j] += xv[j].x * ws4.x + xv[j].y * ws4.y +
                     xv[j].z * ws4.z + xv[j].w * ws4.w;
            ea[j] += xv[j].x * wd4.x + xv[j].y * wd4.y +
                     xv[j].z * wd4.z + xv[j].w * wd4.w;
        }
#pragma unroll
        for (int kk = 0; kk < 4; kk++) {
            float4 w4 = Wl4[(k4 * 4 + kk) * 16 + q];
#pragma unroll
            for (int j = 0; j < GEMM_RR; j++) {
                float xs = COMP(xv[j], kk);
                acc[j].x = fmaf(xs, w4.x, acc[j].x);
                acc[j].y = fmaf(xs, w4.y, acc[j].y);
                acc[j].z = fmaf(xs, w4.z, acc[j].z);
                acc[j].w = fmaf(xs, w4.w, acc[j].w);
            }
        }
    }
#pragma unroll
    for (int j = 0; j < GEMM_RR; j++) {
        int r = r0 + j;
        if (r < N_NODES) {
            half4_t hh = {(_Float16)acc[j].x, (_Float16)acc[j].y,
                          (_Float16)acc[j].z, (_Float16)acc[j].w};
            *(half4_t*)(h16 + (size_t)r * D + q * 4) = hh;   // 8B, coalesced
            if (q == 0) { a_s[r] = sa[j]; a_d[r] = ea[j]; }
        }
    }
}

// one 16-lane group per dst node (4 nodes/wave), lane q = features 4q..4q+3.
// Zero cross-lane ops (lane-redundant weights; broadcast csr/a_s loads).
// 8-deep unrolled gather pipeline + fully-predicated tail (no scalar chain).
__global__ __launch_bounds__(256) void k_aggr(
    const int* __restrict__ off, const int* __restrict__ csr,
    const _Float16* __restrict__ h16, const float* __restrict__ a_s,
    const float* __restrict__ a_d, const float* __restrict__ bias,
    float* __restrict__ out, int do_relu) {
    int node = (blockIdx.x * blockDim.x + threadIdx.x) >> 4;
    int q = threadIdx.x & 15;
    if (node >= N_NODES) return;
    int beg = off[node], end = off[node + 1];
    float ad = a_d[node];
    float s = 0.f;
    float4 acc = {0.f, 0.f, 0.f, 0.f};
    for (int c = beg; c < end; c += 8) {
        int v[8];
        float w[8];
        half4_t hv[8];
#pragma unroll
        for (int i = 0; i < 8; i++) {
            int idx = c + i;
            v[i] = (idx < end) ? csr[idx] : csr[beg];   // clamped: L1-hot
        }
#pragma unroll
        for (int i = 0; i < 8; i++)
            hv[i] = *(const half4_t*)(h16 + (size_t)v[i] * D + q * 4);
#pragma unroll
        for (int i = 0; i < 8; i++) {
            float tv = a_s[v[i]] + ad;
            tv = fmaxf(tv, NEG_SLOPE * tv);             // leaky_relu, slope<1
            w[i] = (c + i < end) ? __expf(tv) : 0.f;    // softmax shift dropped
        }
#pragma unroll
        for (int i = 0; i < 8; i++) {
            s += w[i];
            acc.x = fmaf(w[i], (float)hv[i].x, acc.x);
            acc.y = fmaf(w[i], (float)hv[i].y, acc.y);
            acc.z = fmaf(w[i], (float)hv[i].z, acc.z);
            acc.w = fmaf(w[i], (float)hv[i].w, acc.w);
        }
    }
    float inv = 1.f / (s + SM_EPS);
    float4 b4 = ((const float4*)bias)[q];
    float4 o;
    o.x = fmaf(acc.x, inv, b4.x);
    o.y = fmaf(acc.y, inv, b4.y);
    o.z = fmaf(acc.z, inv, b4.z);
    o.w = fmaf(acc.w, inv, b4.w);
    if (do_relu) {
        o.x = fmaxf(o.x, 0.f); o.y = fmaxf(o.y, 0.f);
        o.z = fmaxf(o.z, 0.f); o.w = fmaxf(o.w, 0.f);
    }
    ((float4*)(out + (size_t)node * D))[q] = o;
}

// ---------------- launch ----------------

extern "C" void kernel_launch(void* const* d_in, const int* in_sizes, int n_in,
                              void* d_out, int out_size, void* d_ws, size_t ws_size,
                              hipStream_t stream) {
    const float* x   = (const float*)d_in[0];
    const int*   ei  = (const int*)d_in[1];
    const float* W1  = (const float*)d_in[2];
    const float* as1 = (const float*)d_in[3];
    const float* ad1 = (const float*)d_in[4];
    const float* b1  = (const float*)d_in[5];
    const float* W2  = (const float*)d_in[6];
    const float* as2 = (const float*)d_in[7];
    const float* ad2 = (const float*)d_in[8];
    const float* b2  = (const float*)d_in[9];
    float* out = (float*)d_out;

    const int* src = ei;
    const int* dst = ei + N_EDGES;

    char* ws = (char*)d_ws;
    size_t o = 0;
    auto alloc = [&](size_t bytes) { void* p = ws + o; o += (bytes + 255) & ~255ull; return p; };
    _Float16* h16 = (_Float16*)alloc((size_t)N_NODES * D * sizeof(_Float16)); // 12.8 MB
    float* a_s   = (float*)alloc(N_NODES * sizeof(float));
    float* a_d   = (float*)alloc(N_NODES * sizeof(float));
    int*   off   = (int*)alloc((N_NODES + 1) * sizeof(int));
    int*   csr   = (int*)alloc(N_EDGES * sizeof(int));                  // 6.4 MB
    int*   gbh   = (int*)alloc(NB * PAD * sizeof(int));
    int*   bbase = (int*)alloc((NB + 1) * sizeof(int));
    int*   bcur  = (int*)alloc(NB * PAD * sizeof(int));
    float* wv    = (float*)alloc(4 * D * sizeof(float));
    // ebuf aliases h16: CSR build completes before k_gemm writes h16
    unsigned* ebuf = (unsigned*)h16;                                    // 6.4 MB < 12.8 MB

    // ---- precompute W@att vectors (both layers) ----
    k_wvec<<<1, 256, 0, stream>>>(W1, as1, ad1, W2, as2, ad2, wv);

    // ---- CSR by dst (two-level counting sort; shared by both layers) ----
    hipMemsetAsync(gbh, 0, NB * PAD * sizeof(int), stream);
    k_bhist   <<<NWG_E, TPB, 0, stream>>>(dst, gbh);
    k_scan_nb <<<1, 256, 0, stream>>>(gbh, bbase, bcur);
    k_bscatter<<<NWG_E, TPB, 0, stream>>>(src, dst, bcur, ebuf);
    k_bcsr    <<<NB, TPB, 0, stream>>>(bbase, ebuf, off, csr);

    // ---- layer 1: x -> out (relu'd) ----
    k_gemm<<<NWG_GEMM, 256, 0, stream>>>(x, W1, wv, h16, a_s, a_d);
    k_aggr<<<(N_NODES * 16 + 255) / 256, 256, 0, stream>>>(off, csr, h16, a_s, a_d, b1, out, 1);

    // ---- layer 2: out -> out ----
    k_gemm<<<NWG_GEMM, 256, 0, stream>>>(out, W2, wv + 2 * D, h16, a_s, a_d);
    k_aggr<<<(N_NODES * 16 + 255) / 256, 256, 0, stream>>>(off, csr, h16, a_s, a_d, b2, out, 0);
}

// Round 10
// 255.903 us; speedup vs baseline: 1.9959x; 1.0879x over previous
//
#include <hip/hip_runtime.h>

#define N_NODES 100000
#define N_EDGES 1600000
#define D 64
#define NEG_SLOPE 0.2f
#define SM_EPS 1e-16f

#define BSHIFT 9
#define BSIZE (1 << BSHIFT)                          // 512 dsts per bucket
#define NB ((N_NODES + BSIZE - 1) >> BSHIFT)         // 196 buckets
#define PAD 16                                        // 64B stride for global counters
#define TPB 256
#define TPB2 512
#define EPT 16
#define TILE (TPB * EPT)                              // 4096 edges per block
#define NWG_E ((N_EDGES + TILE - 1) / TILE)           // 391
#define CSR_CAP 10240                                 // bucket mean 8192, sigma 90

#define GEMM_RR 8                                     // rows per thread
#define GEMM_ROWS 128                                 // rows per block (16 groups x 8)
#define NWG_GEMM ((N_NODES + GEMM_ROWS - 1) / GEMM_ROWS)  // 782

#define COMP(v, kk) ((kk) == 0 ? (v).x : (kk) == 1 ? (v).y : (kk) == 2 ? (v).z : (v).w)

typedef _Float16 half4_t __attribute__((ext_vector_type(4)));   // 8 B

// ---------------- fused gemm body (used by k_front and k_gemm2) ----------------
// h16 = fp16(x @ W); a_s = x.(W@att_src), a_d = x.(W@att_dst), all fused.
// W staged to LDS; wsv/wvd computed inline from the LDS copy (128 threads,
// one 64-dot each). Thread (g=t>>4, q=t&15) owns an 8-row x 4-col tile.
// smraw layout: [0,16384) W as float4; [16384,16640) wvs; [16640,16896) wvd.
__device__ __forceinline__ void gemm_block(
    char* smraw, int bid,
    const float* __restrict__ x, const float* __restrict__ W,
    const float* __restrict__ att_s, const float* __restrict__ att_d,
    _Float16* __restrict__ h16, float* __restrict__ a_s,
    float* __restrict__ a_d) {
    float4* Wl4 = (float4*)smraw;
    float* wvs = (float*)(smraw + 16384);
    float* wvd = wvs + D;
    int t = threadIdx.x;
    const float4* W4 = (const float4*)W;
#pragma unroll
    for (int i = 0; i < 4; i++) Wl4[i * 256 + t] = W4[i * 256 + t];
    __syncthreads();
    if (t < 128) {                         // inline wvec: row (t&63) . att
        int row = t & 63;
        const float4* a4 = (const float4*)((t < 64) ? att_s : att_d);
        float s = 0.f;
#pragma unroll
        for (int q4 = 0; q4 < 16; q4++) {
            float4 wr = Wl4[row * 16 + q4];
            float4 aa = a4[q4];
            s += wr.x * aa.x + wr.y * aa.y + wr.z * aa.z + wr.w * aa.w;
        }
        if (t < 64) wvs[row] = s; else wvd[row] = s;
    }
    __syncthreads();
    int q = t & 15;
    int r0 = bid * GEMM_ROWS + (t >> 4) * GEMM_RR;
    const float4* x4 = (const float4*)x;
    const float4* wvs4 = (const float4*)wvs;
    const float4* wvd4 = (const float4*)wvd;
    float4 acc[GEMM_RR];
    float sa[GEMM_RR], ea[GEMM_RR];
#pragma unroll
    for (int j = 0; j < GEMM_RR; j++) {
        acc[j] = {0.f, 0.f, 0.f, 0.f};
        sa[j] = 0.f; ea[j] = 0.f;
    }
    for (int k4 = 0; k4 < D / 4; k4++) {
        float4 ws4 = wvs4[k4], wd4 = wvd4[k4];
        float4 xv[GEMM_RR];
#pragma unroll
        for (int j = 0; j < GEMM_RR; j++) {
            int r = r0 + j;
            r = (r < N_NODES) ? r : N_NODES - 1;       // clamp (tail block)
            xv[j] = x4[(size_t)r * (D / 4) + k4];      // broadcast across 16 lanes
        }
#pragma unroll
        for (int j = 0; j < GEMM_RR; j++) {
            sa[j] += xv[j].x * ws4.x + xv[j].y * ws4.y +
                     xv[j].z * ws4.z + xv[j].w * ws4.w;
            ea[j] += xv[j].x * wd4.x + xv[j].y * wd4.y +
                     xv[j].z * wd4.z + xv[j].w * wd4.w;
        }
#pragma unroll
        for (int kk = 0; kk < 4; kk++) {
            float4 w4 = Wl4[(k4 * 4 + kk) * 16 + q];
#pragma unroll
            for (int j = 0; j < GEMM_RR; j++) {
                float xs = COMP(xv[j], kk);
                acc[j].x = fmaf(xs, w4.x, acc[j].x);
                acc[j].y = fmaf(xs, w4.y, acc[j].y);
                acc[j].z = fmaf(xs, w4.z, acc[j].z);
                acc[j].w = fmaf(xs, w4.w, acc[j].w);
            }
        }
    }
#pragma unroll
    for (int j = 0; j < GEMM_RR; j++) {
        int r = r0 + j;
        if (r < N_NODES) {
            half4_t hh = {(_Float16)acc[j].x, (_Float16)acc[j].y,
                          (_Float16)acc[j].z, (_Float16)acc[j].w};
            *(half4_t*)(h16 + (size_t)r * D + q * 4) = hh;   // 8B, coalesced
            if (q == 0) { a_s[r] = sa[j]; a_d[r] = ea[j]; }
        }
    }
}

// coarse bucket histogram body (LDS-aggregated, padded global atomics)
__device__ __forceinline__ void bhist_block(
    char* smraw, int bid, const int* __restrict__ dst, int* __restrict__ gbh) {
    int* hist = (int*)smraw;
    int t = threadIdx.x;
    for (int i = t; i < NB; i += TPB) hist[i] = 0;
    __syncthreads();
    int base = bid * TILE;
#pragma unroll
    for (int j = 0; j < EPT; j++) {
        int i = base + j * TPB + t;
        if (i < N_EDGES) atomicAdd(&hist[dst[i] >> BSHIFT], 1);
    }
    __syncthreads();
    for (int i = t; i < NB; i += TPB)
        if (hist[i]) atomicAdd(&gbh[i * PAD], hist[i]);
}

// fused front: gemm(layer1) blocks + bhist blocks in one dispatch (they are
// independent; latency-bound gemm overlaps BW-bound hist on the machine).
__global__ __launch_bounds__(256) void k_front(
    const float* __restrict__ x, const float* __restrict__ W1,
    const float* __restrict__ as1, const float* __restrict__ ad1,
    _Float16* __restrict__ h16, float* __restrict__ a_s,
    float* __restrict__ a_d, const int* __restrict__ dst,
    int* __restrict__ gbh) {
    __shared__ __align__(16) char smraw[16896];
    if (blockIdx.x < NWG_GEMM)
        gemm_block(smraw, blockIdx.x, x, W1, as1, ad1, h16, a_s, a_d);
    else
        bhist_block(smraw, blockIdx.x - NWG_GEMM, dst, gbh);
}

// layer-2 gemm (standalone)
__global__ __launch_bounds__(256) void k_gemm2(
    const float* __restrict__ x, const float* __restrict__ W,
    const float* __restrict__ att_s, const float* __restrict__ att_d,
    _Float16* __restrict__ h16, float* __restrict__ a_s,
    float* __restrict__ a_d) {
    __shared__ __align__(16) char smraw[16896];
    gemm_block(smraw, blockIdx.x, x, W, att_s, att_d, h16, a_s, a_d);
}

// ---------------- CSR build ----------------

__global__ __launch_bounds__(256) void k_scan_nb(const int* __restrict__ gbh,
                                                 int* __restrict__ bbase,
                                                 int* __restrict__ bcur) {
    __shared__ int lds[256];
    int t = threadIdx.x;
    int v = (t < NB) ? gbh[t * PAD] : 0;
    lds[t] = v;
    __syncthreads();
    for (int s = 1; s < 256; s <<= 1) {
        int a = (t >= s) ? lds[t - s] : 0;
        __syncthreads();
        lds[t] += a;
        __syncthreads();
    }
    int excl = lds[t] - v;
    if (t < NB) { bbase[t] = excl; bcur[t * PAD] = excl; }
    if (t == 0) bbase[NB] = N_EDGES;
}

// scatter edges into coarse bucket regions. LDS-staged in bucket-sorted order
// so global writes are contiguous runs per bucket. 512 threads.
__global__ __launch_bounds__(TPB2) void k_bscatter(const int* __restrict__ src,
                                                   const int* __restrict__ dst,
                                                   int* __restrict__ bcur,
                                                   unsigned* __restrict__ ebuf) {
    __shared__ int hist[NB];
    __shared__ int cursor[NB];
    __shared__ int lbase[NB];       // global_base - local_excl per bucket
    __shared__ int tsum[TPB2];
    __shared__ unsigned stage[TILE];      // 16 KB
    __shared__ int stageaddr[TILE];       // 16 KB
    int t = threadIdx.x;
    for (int i = t; i < NB; i += TPB2) hist[i] = 0;
    __syncthreads();
    int base = blockIdx.x * TILE;
#pragma unroll
    for (int j = 0; j < TILE / TPB2; j++) {
        int i = base + j * TPB2 + t;
        if (i < N_EDGES) atomicAdd(&hist[dst[i] >> BSHIFT], 1);
    }
    __syncthreads();
    // exclusive scan of the bucket counts (block-local)
    int v = (t < NB) ? hist[t] : 0;
    tsum[t] = v;
    __syncthreads();
    for (int s = 1; s < TPB2; s <<= 1) {
        int a = (t >= s) ? tsum[t - s] : 0;
        __syncthreads();
        tsum[t] += a;
        __syncthreads();
    }
    int excl = tsum[t] - v;
    if (t < NB) {
        int gb = v ? atomicAdd(&bcur[t * PAD], v) : 0;
        lbase[t] = gb - excl;       // gaddr = lbase[b] + stage_slot
        cursor[t] = excl;
    }
    __syncthreads();
    // scatter into LDS stage (bucket-sorted order within block)
#pragma unroll
    for (int j = 0; j < TILE / TPB2; j++) {
        int i = base + j * TPB2 + t;
        if (i < N_EDGES) {
            int d = dst[i];
            int b = d >> BSHIFT;
            int r = atomicAdd(&cursor[b], 1);           // LDS atomic
            stage[r] = (unsigned)src[i] | ((unsigned)(d & (BSIZE - 1)) << 17);
            stageaddr[r] = lbase[b] + r;
        }
    }
    __syncthreads();
    // write out: consecutive slots -> consecutive global addresses per bucket
    int total = min(TILE, N_EDGES - base);
    for (int s = t; s < total; s += TPB2) ebuf[stageaddr[s]] = stage[s];
}

// per-bucket fine CSR: 512 threads, one per dst slot; LDS-staged scatter,
// perfectly-coalesced final write.
__global__ __launch_bounds__(TPB2) void k_bcsr(const int* __restrict__ bbase,
                                               const unsigned* __restrict__ ebuf,
                                               int* __restrict__ off,
                                               int* __restrict__ csr) {
    __shared__ int dh[BSIZE];   // hist, then cursor
    __shared__ int dl[BSIZE];   // bucket-local exclusive scan
    __shared__ int tsum[TPB2];
    __shared__ int stage[CSR_CAP];   // 40 KB
    int b = blockIdx.x;
    int t = threadIdx.x;
    int beg = bbase[b], end = bbase[b + 1];
    int cnt = end - beg;
    dh[t] = 0;
    __syncthreads();
    for (int i = beg + t; i < end; i += TPB2)
        atomicAdd(&dh[(ebuf[i] >> 17) & (BSIZE - 1)], 1);
    __syncthreads();
    int v = dh[t];
    tsum[t] = v;
    __syncthreads();
    for (int s = 1; s < TPB2; s <<= 1) {
        int a = (t >= s) ? tsum[t - s] : 0;
        __syncthreads();
        tsum[t] += a;
        __syncthreads();
    }
    int excl = tsum[t] - v;
    dl[t] = excl;
    int gd = (b << BSHIFT) + t;
    if (gd < N_NODES) off[gd] = beg + excl;
    if (b == 0 && t == 0) off[N_NODES] = N_EDGES;
    dh[t] = 0;                                  // reset cursors
    __syncthreads();
    if (cnt <= CSR_CAP) {
        // staged: scatter to LDS, then dense coalesced global write
        for (int i = beg + t; i < end; i += TPB2) {
            unsigned pk = ebuf[i];
            int ld = (pk >> 17) & (BSIZE - 1);
            int r = atomicAdd(&dh[ld], 1);      // LDS atomic
            stage[dl[ld] + r] = (int)(pk & 0x1FFFFu);
        }
        __syncthreads();
        for (int s = t; s < cnt; s += TPB2) csr[beg + s] = stage[s];
    } else {
        // fallback (statistically unreachable): direct scatter
        for (int i = beg + t; i < end; i += TPB2) {
            unsigned pk = ebuf[i];
            int ld = (pk >> 17) & (BSIZE - 1);
            int r = atomicAdd(&dh[ld], 1);
            csr[beg + dl[ld] + r] = (int)(pk & 0x1FFFFu);
        }
    }
}

// ---------------- aggregation ----------------

// one 16-lane group per dst node (4 nodes/wave), lane q = features 4q..4q+3.
// Zero cross-lane ops (lane-redundant weights; broadcast csr/a_s loads).
// 8-deep unrolled gather pipeline + fully-predicated tail.
__global__ __launch_bounds__(256) void k_aggr(
    const int* __restrict__ off, const int* __restrict__ csr,
    const _Float16* __restrict__ h16, const float* __restrict__ a_s,
    const float* __restrict__ a_d, const float* __restrict__ bias,
    float* __restrict__ out, int do_relu) {
    int node = (blockIdx.x * blockDim.x + threadIdx.x) >> 4;
    int q = threadIdx.x & 15;
    if (node >= N_NODES) return;
    int beg = off[node], end = off[node + 1];
    float ad = a_d[node];
    float s = 0.f;
    float4 acc = {0.f, 0.f, 0.f, 0.f};
    for (int c = beg; c < end; c += 8) {
        int v[8];
        float w[8];
        half4_t hv[8];
#pragma unroll
        for (int i = 0; i < 8; i++) {
            int idx = c + i;
            v[i] = (idx < end) ? csr[idx] : csr[beg];   // clamped: L1-hot
        }
#pragma unroll
        for (int i = 0; i < 8; i++)
            hv[i] = *(const half4_t*)(h16 + (size_t)v[i] * D + q * 4);
#pragma unroll
        for (int i = 0; i < 8; i++) {
            float tv = a_s[v[i]] + ad;
            tv = fmaxf(tv, NEG_SLOPE * tv);             // leaky_relu, slope<1
            w[i] = (c + i < end) ? __expf(tv) : 0.f;    // softmax shift dropped
        }
#pragma unroll
        for (int i = 0; i < 8; i++) {
            s += w[i];
            acc.x = fmaf(w[i], (float)hv[i].x, acc.x);
            acc.y = fmaf(w[i], (float)hv[i].y, acc.y);
            acc.z = fmaf(w[i], (float)hv[i].z, acc.z);
            acc.w = fmaf(w[i], (float)hv[i].w, acc.w);
        }
    }
    float inv = 1.f / (s + SM_EPS);
    float4 b4 = ((const float4*)bias)[q];
    float4 o;
    o.x = fmaf(acc.x, inv, b4.x);
    o.y = fmaf(acc.y, inv, b4.y);
    o.z = fmaf(acc.z, inv, b4.z);
    o.w = fmaf(acc.w, inv, b4.w);
    if (do_relu) {
        o.x = fmaxf(o.x, 0.f); o.y = fmaxf(o.y, 0.f);
        o.z = fmaxf(o.z, 0.f); o.w = fmaxf(o.w, 0.f);
    }
    ((float4*)(out + (size_t)node * D))[q] = o;
}

// ---------------- launch ----------------

extern "C" void kernel_launch(void* const* d_in, const int* in_sizes, int n_in,
                              void* d_out, int out_size, void* d_ws, size_t ws_size,
                              hipStream_t stream) {
    const float* x   = (const float*)d_in[0];
    const int*   ei  = (const int*)d_in[1];
    const float* W1  = (const float*)d_in[2];
    const float* as1 = (const float*)d_in[3];
    const float* ad1 = (const float*)d_in[4];
    const float* b1  = (const float*)d_in[5];
    const float* W2  = (const float*)d_in[6];
    const float* as2 = (const float*)d_in[7];
    const float* ad2 = (const float*)d_in[8];
    const float* b2  = (const float*)d_in[9];
    float* out = (float*)d_out;

    const int* src = ei;
    const int* dst = ei + N_EDGES;

    char* ws = (char*)d_ws;
    size_t o = 0;
    auto alloc = [&](size_t bytes) { void* p = ws + o; o += (bytes + 255) & ~255ull; return p; };
    _Float16* h16 = (_Float16*)alloc((size_t)N_NODES * D * sizeof(_Float16)); // 12.8 MB
    unsigned* ebuf = (unsigned*)alloc(N_EDGES * sizeof(unsigned));            // 6.4 MB (no longer aliased: k_front writes h16 concurrently with CSR build)
    float* a_s   = (float*)alloc(N_NODES * sizeof(float));
    float* a_d   = (float*)alloc(N_NODES * sizeof(float));
    int*   off   = (int*)alloc((N_NODES + 1) * sizeof(int));
    int*   csr   = (int*)alloc(N_EDGES * sizeof(int));                        // 6.4 MB
    int*   gbh   = (int*)alloc(NB * PAD * sizeof(int));
    int*   bbase = (int*)alloc((NB + 1) * sizeof(int));
    int*   bcur  = (int*)alloc(NB * PAD * sizeof(int));

    // ---- fused: layer-1 gemm (+inline wvec) || coarse bucket histogram ----
    hipMemsetAsync(gbh, 0, NB * PAD * sizeof(int), stream);
    k_front<<<NWG_GEMM + NWG_E, 256, 0, stream>>>(x, W1, as1, ad1, h16, a_s, a_d, dst, gbh);

    // ---- CSR by dst (shared by both layers) ----
    k_scan_nb <<<1, 256, 0, stream>>>(gbh, bbase, bcur);
    k_bscatter<<<NWG_E, TPB2, 0, stream>>>(src, dst, bcur, ebuf);
    k_bcsr    <<<NB, TPB2, 0, stream>>>(bbase, ebuf, off, csr);

    // ---- layer 1 aggregation: -> out (relu'd) ----
    k_aggr<<<(N_NODES * 16 + 255) / 256, 256, 0, stream>>>(off, csr, h16, a_s, a_d, b1, out, 1);

    // ---- layer 2 ----
    k_gemm2<<<NWG_GEMM, 256, 0, stream>>>(out, W2, as2, ad2, h16, a_s, a_d);
    k_aggr<<<(N_NODES * 16 + 255) / 256, 256, 0, stream>>>(off, csr, h16, a_s, a_d, b2, out, 0);
}